// Round 10
// baseline (670.998 us; speedup 1.0000x reference)
//
#include <hip/hip_runtime.h>
#include <cstdint>
#include <cstddef>

#define N_NODES 89250
#define M_PAD   89344   // 349 * 256
#define F0 500
#define F1 512
#define F2 256
#define F3 7
#define KP 512          // padded K for the MFMA GEMMs

typedef __attribute__((ext_vector_type(8))) short bf16x8;   // 8 bf16 = 4 VGPRs
typedef __attribute__((ext_vector_type(4))) float f32x4;

static inline int cdiv_i(int a, int b) { return (a + b - 1) / b; }

__device__ __forceinline__ unsigned short f2b(float f) {
  unsigned int u = __float_as_uint(f);
  u = (u + 0x7FFFu + ((u >> 16) & 1u)) >> 16;
  return (unsigned short)u;
}
__device__ __forceinline__ float b2f(unsigned short h) {
  return __uint_as_float(((unsigned int)h) << 16);
}

// ---------------- CSR build ----------------
__global__ void degree_kernel(const int* __restrict__ dst, int* __restrict__ cnt, int E) {
  int stride = gridDim.x * blockDim.x;
  for (int i = blockIdx.x * blockDim.x + threadIdx.x; i < E; i += stride)
    atomicAdd(&cnt[dst[i]], 1);
}

__global__ __launch_bounds__(1024) void scan_partial(const int* __restrict__ cnt,
                                                     int* __restrict__ row_ptr,
                                                     int* __restrict__ bsum, int n) {
  __shared__ int sm[1024];
  const int i = blockIdx.x * 1024 + threadIdx.x;
  const int v = (i < n) ? cnt[i] : 0;
  sm[threadIdx.x] = v;
  __syncthreads();
  for (int off = 1; off < 1024; off <<= 1) {
    int t = (threadIdx.x >= off) ? sm[threadIdx.x - off] : 0;
    __syncthreads();
    sm[threadIdx.x] += t;
    __syncthreads();
  }
  if (i < n) row_ptr[i] = sm[threadIdx.x] - v;    // block-local exclusive
  if (threadIdx.x == 1023) bsum[blockIdx.x] = sm[1023];
}

__global__ __launch_bounds__(1024) void scan_bsums(int* __restrict__ bsum, int nb) {
  __shared__ int sm[1024];
  const int v = (threadIdx.x < nb) ? bsum[threadIdx.x] : 0;
  sm[threadIdx.x] = v;
  __syncthreads();
  for (int off = 1; off < 1024; off <<= 1) {
    int t = (threadIdx.x >= off) ? sm[threadIdx.x - off] : 0;
    __syncthreads();
    sm[threadIdx.x] += t;
    __syncthreads();
  }
  if (threadIdx.x < nb) bsum[threadIdx.x] = sm[threadIdx.x] - v;  // exclusive
}

// adds block offsets AND initializes cursor = row_ptr (saves a pass)
__global__ __launch_bounds__(1024) void scan_add(int* __restrict__ row_ptr,
                                                 const int* __restrict__ bsum,
                                                 int* __restrict__ cursor,
                                                 int n, int total) {
  const int i = blockIdx.x * 1024 + threadIdx.x;
  if (i < n) {
    const int v = row_ptr[i] + bsum[i >> 10];
    row_ptr[i] = v;
    cursor[i] = v;
  }
  if (i == 0) row_ptr[n] = total;
}

__global__ void fill_kernel(const int* __restrict__ src, const int* __restrict__ dst,
                            int* __restrict__ cursor, int* __restrict__ csr_src, int E) {
  int stride = gridDim.x * blockDim.x;
  for (int i = blockIdx.x * blockDim.x + threadIdx.x; i < E; i += stride) {
    const int p = atomicAdd(&cursor[dst[i]], 1);
    csr_src[p] = src[i];
  }
}

// ---------------- fused conversion: x + all weights (block-range split) ----------------
#define XBLK (M_PAD * 64 / 256)     // 22336
__global__ __launch_bounds__(256) void prep_kernel(
    const float* __restrict__ x,
    const float* __restrict__ wl1, const float* __restrict__ wr1,
    const float* __restrict__ wl2, const float* __restrict__ wr2,
    const float* __restrict__ wl3, const float* __restrict__ wr3,
    unsigned short* __restrict__ xb,
    unsigned short* __restrict__ wl1b, unsigned short* __restrict__ wr1b,
    unsigned short* __restrict__ w2b, unsigned short* __restrict__ w3b)
{
  if (blockIdx.x < XBLK) {
    const int idx = blockIdx.x * 256 + threadIdx.x;   // uint4 granule
    const int node = idx >> 6;
    const int c8 = (idx & 63) * 8;
    unsigned short r[8];
#pragma unroll
    for (int j = 0; j < 8; ++j) {
      const int c = c8 + j;
      float v = 0.0f;
      if (node < N_NODES && c < F0) v = x[(size_t)node * F0 + c];
      r[j] = f2b(v);
    }
    *reinterpret_cast<uint4*>(xb + (size_t)node * KP + c8) = *reinterpret_cast<const uint4*>(r);
    return;
  }
  int idx = (blockIdx.x - XBLK) * 256 + threadIdx.x;
  const int S1 = F1 * KP;          // 262144, covers wl1 AND wr1
  if (idx < S1) {
    const int j = idx >> 9, k = idx & 511;
    const bool in = (k < F0);
    wl1b[idx] = in ? f2b(wl1[(size_t)j * F0 + k]) : (unsigned short)0;
    wr1b[idx] = in ? f2b(wr1[(size_t)j * F0 + k]) : (unsigned short)0;
    return;
  }
  idx -= S1;
  const int S2 = F2 * KP;          // 131072, covers wl2 AND wr2 (K=512 exact)
  if (idx < S2) {
    w2b[idx] = f2b(wl2[idx]);
    w2b[S2 + idx] = f2b(wr2[idx]);
    return;
  }
  idx -= S2;
  if (idx < 16 * 256) {
    const int j = idx >> 8, k = idx & 255;
    float v = 0.0f;
    if (j < 7) v = wl3[(size_t)j * F2 + k];
    else if (j >= 8 && j < 15) v = wr3[(size_t)(j - 8) * F2 + k];
    w3b[idx] = f2b(v);
  }
}

// ---------------- gather-mean (bf16 in/out, f32 accum), C=512, wave per node ----------------
__global__ __launch_bounds__(256) void gather_mean_bf512(
    const unsigned short* __restrict__ xb, const int* __restrict__ row_ptr,
    const int* __restrict__ csr_src, unsigned short* __restrict__ aggb)
{
  const int node = blockIdx.x * 4 + (threadIdx.x >> 6);
  const int t = threadIdx.x & 63;
  if (node >= M_PAD) return;
  if (node >= N_NODES) {                // zero pad rows (ws is not re-zeroed between replays)
    *reinterpret_cast<uint4*>(aggb + (size_t)node * 512 + t * 8) = make_uint4(0, 0, 0, 0);
    return;
  }
  const int beg = row_ptr[node];
  const int end = row_ptr[node + 1];
  float acc[8] = {0.f, 0.f, 0.f, 0.f, 0.f, 0.f, 0.f, 0.f};
  for (int j = beg; j < end; j += 8) {
    uint4 v[8];
    float m[8];
#pragma unroll
    for (int u = 0; u < 8; ++u) {
      const int e = min(j + u, end - 1);
      m[u] = (j + u < end) ? 1.0f : 0.0f;
      v[u] = *reinterpret_cast<const uint4*>(xb + (size_t)csr_src[e] * 512 + t * 8);
    }
#pragma unroll
    for (int u = 0; u < 8; ++u) {
      const unsigned int w[4] = {v[u].x, v[u].y, v[u].z, v[u].w};
#pragma unroll
      for (int q = 0; q < 4; ++q) {
        acc[2 * q]     = fmaf(m[u], b2f((unsigned short)(w[q] & 0xFFFF)), acc[2 * q]);
        acc[2 * q + 1] = fmaf(m[u], b2f((unsigned short)(w[q] >> 16)),    acc[2 * q + 1]);
      }
    }
  }
  const int deg = end - beg;
  const float inv = 1.0f / (float)(deg > 1 ? deg : 1);
  unsigned short r[8];
#pragma unroll
  for (int q = 0; q < 8; ++q) r[q] = f2b(acc[q] * inv);
  *reinterpret_cast<uint4*>(aggb + (size_t)node * 512 + t * 8) = *reinterpret_cast<const uint4*>(r);
}

// ---------------- 256x256 8-wave MFMA GEMM, per-phase interleaved staging (faithful T3/T4) ----------------
// Per K-tile (4 phases): each phase {stage ONE half-tile of tile t+1 (2 gload_lds), ds_read
// fragment subtile, 16 MFMA/wave}. One vmcnt(0)+s_barrier per K-tile at tile start — at that
// point only tile t's loads (issued a full tile earlier) are outstanding, so nothing young drains.
// nt=16: C = A1@B1.T + A2@B2.T (t<8: pair1, t>=8: pair2). nt=8: single pair.
__global__ __launch_bounds__(512) void gemm_mfma256(
    const unsigned short* __restrict__ A1, const unsigned short* __restrict__ A2,
    const unsigned short* __restrict__ B1, const unsigned short* __restrict__ B2,
    const float* __restrict__ bias, unsigned short* __restrict__ Cout,
    int J, int nt, int fuse, int relu)
{
  __shared__ __align__(16) unsigned short Alds[2][256 * 64];
  __shared__ __align__(16) unsigned short Blds[2][256 * 64];
  const int tid = threadIdx.x;
  const int lane = tid & 63;
  const int w = tid >> 6;             // 8 waves
  const int wm = w >> 2;              // 2 row-groups of 128
  const int wn = w & 3;               // 4 col-groups of 64

  // bijective XCD swizzle (m204) over col-major flatten (A-panel L2 reuse)
  int wg = blockIdx.x;
  {
    const int nwg = gridDim.x;
    const int q = nwg >> 3, r = nwg & 7;
    const int xcd = wg & 7, o = wg >> 3;
    wg = (xcd < r ? xcd * (q + 1) : r * (q + 1) + (xcd - r) * q) + o;
  }
  const int ncol = J >> 8;
  const int brow = (wg / ncol) * 256;
  const int bcol = (wg % ncol) * 256;

  f32x4 acc[8][4];
#pragma unroll
  for (int m = 0; m < 8; ++m)
#pragma unroll
    for (int n = 0; n < 4; ++n) acc[m][n] = (f32x4){0.f, 0.f, 0.f, 0.f};

  const int fr = lane & 15;
  const int fk = lane >> 4;
  const int srow = lane >> 3;             // row within 8-row stripe
  const int schunk = (lane & 7) ^ srow;   // T2 pre-swizzled source chunk (rule 21)

  // stage half-tile `which` of tile t: 0=Ah0, 1=Bh0, 2=Ah1, 3=Bh1 (2 gload_lds each)
  auto STAGE_H = [&](int t, int which) {
    const int h = which >> 1;
    const int k0 = (t & 7) * 64;
    const int buf = t & 1;
    const unsigned short* __restrict__ src;
    unsigned short* ldsb;
    if (which & 1) { src = (t < 8) ? B1 : B2; ldsb = Blds[buf]; }
    else           { src = (t < 8) ? A1 : A2; ldsb = Alds[buf]; }
    const int gbase = (which & 1) ? bcol : brow;
#pragma unroll
    for (int i = 0; i < 2; ++i) {
      const int rbase = h * 128 + i * 64 + w * 8;   // wave-uniform 8-row stripe
      const int row = rbase + srow;
      __builtin_amdgcn_global_load_lds(
          (const __attribute__((address_space(1))) unsigned int*)(src + (size_t)(gbase + row) * KP + k0 + schunk * 8),
          (__attribute__((address_space(3))) unsigned int*)(ldsb + rbase * 64),
          16, 0, 0);
    }
  };

  // prologue: stage tile 0 fully (8 loads/thread... 8 wave-instructions, 2 per half-tile)
#pragma unroll
  for (int p = 0; p < 4; ++p) STAGE_H(0, p);

  for (int t = 0; t < nt; ++t) {
    // only tile t's loads are outstanding here (t+1's not yet issued): counted-safe drain
    asm volatile("s_waitcnt vmcnt(0)" ::: "memory");
    asm volatile("s_barrier" ::: "memory");   // buf ready for all waves; buf^1 reads finished
    const int buf = t & 1;
    bf16x8 bb[4];
#pragma unroll
    for (int p = 0; p < 4; ++p) {             // phase: stage ∥ ds_read ∥ 16 MFMA
      if (t + 1 < nt) STAGE_H(t + 1, p);
      const int mh = p & 1;                   // row-half of the wave's 128 rows
      const int ks = p >> 1;                  // k-slice
      bf16x8 a[4];
#pragma unroll
      for (int m = 0; m < 4; ++m) {
        const int row = wm * 128 + (mh * 4 + m) * 16 + fr;
        a[m] = *reinterpret_cast<const bf16x8*>(&Alds[buf][row * 64 + (((ks * 4 + fk) ^ (row & 7)) * 8)]);
      }
      if (mh == 0) {                          // reload B frags once per k-slice
#pragma unroll
        for (int n = 0; n < 4; ++n) {
          const int row = wn * 64 + n * 16 + fr;
          bb[n] = *reinterpret_cast<const bf16x8*>(&Blds[buf][row * 64 + (((ks * 4 + fk) ^ (row & 7)) * 8)]);
        }
      }
      __builtin_amdgcn_s_setprio(1);
#pragma unroll
      for (int m = 0; m < 4; ++m)
#pragma unroll
        for (int n = 0; n < 4; ++n)
          acc[mh * 4 + m][n] = __builtin_amdgcn_mfma_f32_16x16x32_bf16(a[m], bb[n], acc[mh * 4 + m][n], 0, 0, 0);
      __builtin_amdgcn_s_setprio(0);
    }
  }

  // epilogue: C/D layout col=lane&15, row=(lane>>4)*4+i  [m89-verified]
  const int crow0 = brow + wm * 128 + (lane >> 4) * 4;
  const int ccol0 = bcol + wn * 64 + fr;
#pragma unroll
  for (int n = 0; n < 4; ++n) {
    const int col = ccol0 + n * 16;
    const float bv = fuse ? bias[col] : 0.0f;
#pragma unroll
    for (int m = 0; m < 8; ++m) {
#pragma unroll
      for (int i = 0; i < 4; ++i) {
        const int row = crow0 + m * 16 + i;
        float v = acc[m][n][i] + bv;
        if (relu) v = fmaxf(v, 0.0f);
        Cout[(size_t)row * J + col] = f2b(v);
      }
    }
  }
}

// ---------------- fused layer-2 combine + layer-3 projection ----------------
__global__ __launch_bounds__(256) void combine2p3_kernel(
    const unsigned short* __restrict__ y, const int* __restrict__ row_ptr,
    const int* __restrict__ csr_src, const float* __restrict__ bias,
    const unsigned short* __restrict__ w3b, unsigned short* __restrict__ y3)
{
  __shared__ unsigned short w3s[16 * 256];
  {
    const int t0 = threadIdx.x * 16;
    *reinterpret_cast<uint4*>(&w3s[t0])     = *reinterpret_cast<const uint4*>(&w3b[t0]);
    *reinterpret_cast<uint4*>(&w3s[t0 + 8]) = *reinterpret_cast<const uint4*>(&w3b[t0 + 8]);
  }
  __syncthreads();

  const int node = blockIdx.x * 8 + (threadIdx.x >> 5);
  const int t = threadIdx.x & 31;        // 8 channels each -> 256
  if (node >= N_NODES) return;
  const int beg = row_ptr[node];
  const int end = row_ptr[node + 1];
  float acc[8] = {0.f, 0.f, 0.f, 0.f, 0.f, 0.f, 0.f, 0.f};
  for (int j = beg; j < end; j += 8) {
    uint4 v[8];
    float m[8];
#pragma unroll
    for (int u = 0; u < 8; ++u) {
      const int e = min(j + u, end - 1);
      m[u] = (j + u < end) ? 1.0f : 0.0f;
      v[u] = *reinterpret_cast<const uint4*>(y + (size_t)csr_src[e] * 512 + t * 8);
    }
#pragma unroll
    for (int u = 0; u < 8; ++u) {
      const unsigned int w[4] = {v[u].x, v[u].y, v[u].z, v[u].w};
#pragma unroll
      for (int q = 0; q < 4; ++q) {
        acc[2 * q]     = fmaf(m[u], b2f((unsigned short)(w[q] & 0xFFFF)), acc[2 * q]);
        acc[2 * q + 1] = fmaf(m[u], b2f((unsigned short)(w[q] >> 16)),    acc[2 * q + 1]);
      }
    }
  }
  const int deg = end - beg;
  const float inv = 1.0f / (float)(deg > 1 ? deg : 1);
  const uint4 rv = *reinterpret_cast<const uint4*>(y + (size_t)node * 512 + 256 + t * 8);
  const unsigned int ru[4] = {rv.x, rv.y, rv.z, rv.w};
  float c[8];
#pragma unroll
  for (int q = 0; q < 4; ++q) {
    const float y0 = b2f((unsigned short)(ru[q] & 0xFFFF));
    const float y1 = b2f((unsigned short)(ru[q] >> 16));
    c[2 * q]     = fmaxf(acc[2 * q] * inv + y0 + bias[t * 8 + 2 * q], 0.0f);
    c[2 * q + 1] = fmaxf(acc[2 * q + 1] * inv + y1 + bias[t * 8 + 2 * q + 1], 0.0f);
  }
#pragma unroll
  for (int jj = 0; jj < 14; ++jj) {
    const int row = jj + (jj >= 7 ? 1 : 0);      // skip padding rows 7/15
    const uint4 wv = *reinterpret_cast<const uint4*>(&w3s[row * 256 + t * 8]);
    const unsigned int wu[4] = {wv.x, wv.y, wv.z, wv.w};
    float s = 0.0f;
#pragma unroll
    for (int q = 0; q < 4; ++q) {
      s = fmaf(c[2 * q],     b2f((unsigned short)(wu[q] & 0xFFFF)), s);
      s = fmaf(c[2 * q + 1], b2f((unsigned short)(wu[q] >> 16)),    s);
    }
#pragma unroll
    for (int m = 1; m < 32; m <<= 1) s += __shfl_xor(s, m, 64);
    if (t == 0) y3[(size_t)node * 16 + row] = f2b(s);
  }
}

// ---------------- combine layer 3: out = mean-gather(y3[:, 0..6]) + y3[i, 8..14] + b3 ----------------
__global__ __launch_bounds__(256) void combine3_kernel(
    const unsigned short* __restrict__ y3, const int* __restrict__ row_ptr,
    const int* __restrict__ csr_src, const float* __restrict__ b3,
    float* __restrict__ out, int N)
{
  const int node = blockIdx.x * 4 + (threadIdx.x >> 6);
  const int lane = threadIdx.x & 63;
  if (node >= N) return;
  const int beg = row_ptr[node];
  const int end = row_ptr[node + 1];
  float acc[7] = {0.f, 0.f, 0.f, 0.f, 0.f, 0.f, 0.f};
  for (int j = beg + lane; j < end; j += 64) {
    const int s = csr_src[j];
    const uint4 v = *reinterpret_cast<const uint4*>(y3 + (size_t)s * 16);
    const unsigned int u[4] = {v.x, v.y, v.z, v.w};
#pragma unroll
    for (int q = 0; q < 7; ++q) {
      const unsigned short hw = (unsigned short)((u[q >> 1] >> ((q & 1) * 16)) & 0xFFFF);
      acc[q] += b2f(hw);
    }
  }
#pragma unroll
  for (int q = 0; q < 7; ++q)
#pragma unroll
    for (int m = 1; m < 64; m <<= 1)
      acc[q] += __shfl_xor(acc[q], m, 64);
  if (lane == 0) {
    const int deg = end - beg;
    const float inv = 1.0f / (float)(deg > 1 ? deg : 1);
    const uint4 rv = *reinterpret_cast<const uint4*>(y3 + (size_t)node * 16 + 8);
    const unsigned int ru[4] = {rv.x, rv.y, rv.z, rv.w};
#pragma unroll
    for (int q = 0; q < 7; ++q) {
      const float self = b2f((unsigned short)((ru[q >> 1] >> ((q & 1) * 16)) & 0xFFFF));
      out[(size_t)node * F3 + q] = acc[q] * inv + self + b3[q];
    }
  }
}

extern "C" void kernel_launch(void* const* d_in, const int* in_sizes, int n_in,
                              void* d_out, int out_size, void* d_ws, size_t ws_size,
                              hipStream_t stream) {
  const float* x    = (const float*)d_in[0];
  const int*   ei   = (const int*)d_in[1];
  const float* w_l1 = (const float*)d_in[2];
  const float* w_r1 = (const float*)d_in[3];
  const float* b1   = (const float*)d_in[4];
  const float* w_l2 = (const float*)d_in[5];
  const float* w_r2 = (const float*)d_in[6];
  const float* b2   = (const float*)d_in[7];
  const float* w_l3 = (const float*)d_in[8];
  const float* w_r3 = (const float*)d_in[9];
  const float* b3   = (const float*)d_in[10];
  float* out = (float*)d_out;

  const int E = in_sizes[1] / 2;
  const int* src = ei;
  const int* dst = ei + E;

  // ---- workspace carve-up
  char* p = (char*)d_ws;
  int* row_ptr = (int*)p;           p += (size_t)(N_NODES + 1) * 4;
  int* cnt     = (int*)p;           p += (size_t)N_NODES * 4;
  int* bsum    = (int*)p;           p += 1024 * 4;
  int* csr_src = (int*)p;           p += (size_t)E * 4;
  p = (char*)(((uintptr_t)p + 255) & ~(uintptr_t)255);
  unsigned short* xb   = (unsigned short*)p;  p += (size_t)M_PAD * KP * 2;  // also reused as y2
  unsigned short* aggb = (unsigned short*)p;  p += (size_t)M_PAD * KP * 2;
  unsigned short* h1b  = (unsigned short*)p;  p += (size_t)M_PAD * KP * 2;  // also reused as y3
  unsigned short* wl1b = (unsigned short*)p;  p += (size_t)F1 * KP * 2;
  unsigned short* wr1b = (unsigned short*)p;  p += (size_t)F1 * KP * 2;
  unsigned short* w2b  = (unsigned short*)p;  p += (size_t)F1 * KP * 2;     // concat [wl2; wr2] -> 512 rows
  unsigned short* w3b  = (unsigned short*)p;  p += (size_t)16 * F2 * 2;     // [16,256]

  unsigned short* y2  = xb;     // [M_PAD, 512]; xb dead after GEMM1
  unsigned short* y3  = h1b;    // [M_PAD, 16];  h1b dead after GEMM2

  const int nb = cdiv_i(N_NODES, 1024);   // 88

  // ---- CSR build
  hipMemsetAsync(cnt, 0, (size_t)N_NODES * sizeof(int), stream);
  degree_kernel<<<cdiv_i(E, 256), 256, 0, stream>>>(dst, cnt, E);
  scan_partial<<<nb, 1024, 0, stream>>>(cnt, row_ptr, bsum, N_NODES);
  scan_bsums<<<1, 1024, 0, stream>>>(bsum, nb);
  scan_add<<<nb, 1024, 0, stream>>>(row_ptr, bsum, cnt, N_NODES, E);   // cnt becomes cursor
  fill_kernel<<<cdiv_i(E, 256), 256, 0, stream>>>(src, dst, cnt, csr_src, E);

  // ---- conversions (x + all weights, one kernel)
  {
    const int wblocks = cdiv_i(F1 * KP + F2 * KP + 16 * F2, 256);   // 1552
    prep_kernel<<<XBLK + wblocks, 256, 0, stream>>>(
        x, w_l1, w_r1, w_l2, w_r2, w_l3, w_r3, xb, wl1b, wr1b, w2b, w3b);
  }

  // ---- layer 1: agg = mean-gather(x);  h1 = relu(agg@wl1.T + x@wr1.T + b1)
  gather_mean_bf512<<<cdiv_i(M_PAD, 4), 256, 0, stream>>>(xb, row_ptr, csr_src, aggb);
  gemm_mfma256<<<(M_PAD / 256) * (F1 / 256), 512, 0, stream>>>(
      aggb, xb, wl1b, wr1b, b1, h1b, F1, 16, 1, 1);

  // ---- layer 2 (aggregate AFTER projection): y2 = h1 @ [wl2; wr2].T
  gemm_mfma256<<<(M_PAD / 256) * (512 / 256), 512, 0, stream>>>(
      h1b, h1b, w2b, w2b, (const float*)nullptr, y2, 512, 8, 0, 0);
  // fused: combine layer 2 + project layer 3 (h2 never materialized)
  combine2p3_kernel<<<cdiv_i(N_NODES, 8), 256, 0, stream>>>(y2, row_ptr, csr_src, b2, w3b, y3);

  // ---- combine layer 3
  combine3_kernel<<<cdiv_i(N_NODES, 4), 256, 0, stream>>>(y3, row_ptr, csr_src, b3, out, N_NODES);
}

// Round 11
// 657.614 us; speedup vs baseline: 1.0204x; 1.0204x over previous
//
#include <hip/hip_runtime.h>
#include <cstdint>
#include <cstddef>

#define N_NODES 89250
#define M_PAD   89344   // 698 * 128
#define F0 500
#define F1 512
#define F2 256
#define F3 7
#define KP 512          // padded K for the MFMA GEMMs

typedef __attribute__((ext_vector_type(8))) short bf16x8;   // 8 bf16 = 4 VGPRs
typedef __attribute__((ext_vector_type(4))) float f32x4;

static inline int cdiv_i(int a, int b) { return (a + b - 1) / b; }

__device__ __forceinline__ unsigned short f2b(float f) {
  unsigned int u = __float_as_uint(f);
  u = (u + 0x7FFFu + ((u >> 16) & 1u)) >> 16;
  return (unsigned short)u;
}
__device__ __forceinline__ float b2f(unsigned short h) {
  return __uint_as_float(((unsigned int)h) << 16);
}

// ---------------- CSR build ----------------
__global__ void degree_kernel(const int* __restrict__ dst, int* __restrict__ cnt, int E) {
  int stride = gridDim.x * blockDim.x;
  for (int i = blockIdx.x * blockDim.x + threadIdx.x; i < E; i += stride)
    atomicAdd(&cnt[__builtin_nontemporal_load(dst + i)], 1);
}

__global__ __launch_bounds__(1024) void scan_partial(const int* __restrict__ cnt,
                                                     int* __restrict__ row_ptr,
                                                     int* __restrict__ bsum, int n) {
  __shared__ int sm[1024];
  const int i = blockIdx.x * 1024 + threadIdx.x;
  const int v = (i < n) ? cnt[i] : 0;
  sm[threadIdx.x] = v;
  __syncthreads();
  for (int off = 1; off < 1024; off <<= 1) {
    int t = (threadIdx.x >= off) ? sm[threadIdx.x - off] : 0;
    __syncthreads();
    sm[threadIdx.x] += t;
    __syncthreads();
  }
  if (i < n) row_ptr[i] = sm[threadIdx.x] - v;    // block-local exclusive
  if (threadIdx.x == 1023) bsum[blockIdx.x] = sm[1023];
}

__global__ __launch_bounds__(1024) void scan_bsums(int* __restrict__ bsum, int nb) {
  __shared__ int sm[1024];
  const int v = (threadIdx.x < nb) ? bsum[threadIdx.x] : 0;
  sm[threadIdx.x] = v;
  __syncthreads();
  for (int off = 1; off < 1024; off <<= 1) {
    int t = (threadIdx.x >= off) ? sm[threadIdx.x - off] : 0;
    __syncthreads();
    sm[threadIdx.x] += t;
    __syncthreads();
  }
  if (threadIdx.x < nb) bsum[threadIdx.x] = sm[threadIdx.x] - v;  // exclusive
}

// adds block offsets AND initializes cursor = row_ptr (saves a pass)
__global__ __launch_bounds__(1024) void scan_add(int* __restrict__ row_ptr,
                                                 const int* __restrict__ bsum,
                                                 int* __restrict__ cursor,
                                                 int n, int total) {
  const int i = blockIdx.x * 1024 + threadIdx.x;
  if (i < n) {
    const int v = row_ptr[i] + bsum[i >> 10];
    row_ptr[i] = v;
    cursor[i] = v;
  }
  if (i == 0) row_ptr[n] = total;
}

__global__ void fill_kernel(const int* __restrict__ src, const int* __restrict__ dst,
                            int* __restrict__ cursor, int* __restrict__ csr_src, int E) {
  int stride = gridDim.x * blockDim.x;
  for (int i = blockIdx.x * blockDim.x + threadIdx.x; i < E; i += stride) {
    const int p = atomicAdd(&cursor[dst[i]], 1);
    csr_src[p] = src[i];
  }
}

// ---------------- fused conversion: x + all weights (block-range split) ----------------
// f32 sources are read exactly once -> nontemporal loads (keep L2/L3 for bf16 working set)
#define XBLK (M_PAD * 64 / 256)     // 22336
__global__ __launch_bounds__(256) void prep_kernel(
    const float* __restrict__ x,
    const float* __restrict__ wl1, const float* __restrict__ wr1,
    const float* __restrict__ wl2, const float* __restrict__ wr2,
    const float* __restrict__ wl3, const float* __restrict__ wr3,
    unsigned short* __restrict__ xb,
    unsigned short* __restrict__ wl1b, unsigned short* __restrict__ wr1b,
    unsigned short* __restrict__ w2b, unsigned short* __restrict__ w3b)
{
  if (blockIdx.x < XBLK) {
    const int idx = blockIdx.x * 256 + threadIdx.x;   // uint4 granule
    const int node = idx >> 6;
    const int c8 = (idx & 63) * 8;
    unsigned short r[8];
#pragma unroll
    for (int j = 0; j < 8; ++j) {
      const int c = c8 + j;
      float v = 0.0f;
      if (node < N_NODES && c < F0) v = __builtin_nontemporal_load(x + (size_t)node * F0 + c);
      r[j] = f2b(v);
    }
    *reinterpret_cast<uint4*>(xb + (size_t)node * KP + c8) = *reinterpret_cast<const uint4*>(r);
    return;
  }
  int idx = (blockIdx.x - XBLK) * 256 + threadIdx.x;
  const int S1 = F1 * KP;          // 262144, covers wl1 AND wr1
  if (idx < S1) {
    const int j = idx >> 9, k = idx & 511;
    const bool in = (k < F0);
    wl1b[idx] = in ? f2b(__builtin_nontemporal_load(wl1 + (size_t)j * F0 + k)) : (unsigned short)0;
    wr1b[idx] = in ? f2b(__builtin_nontemporal_load(wr1 + (size_t)j * F0 + k)) : (unsigned short)0;
    return;
  }
  idx -= S1;
  const int S2 = F2 * KP;          // 131072, covers wl2 AND wr2 (K=512 exact)
  if (idx < S2) {
    w2b[idx] = f2b(__builtin_nontemporal_load(wl2 + idx));
    w2b[S2 + idx] = f2b(__builtin_nontemporal_load(wr2 + idx));
    return;
  }
  idx -= S2;
  if (idx < 16 * 256) {
    const int j = idx >> 8, k = idx & 255;
    float v = 0.0f;
    if (j < 7) v = wl3[(size_t)j * F2 + k];
    else if (j >= 8 && j < 15) v = wr3[(size_t)(j - 8) * F2 + k];
    w3b[idx] = f2b(v);
  }
}

// ---------------- gather-mean (bf16 in/out, f32 accum), C=512, wave per node ----------------
__global__ __launch_bounds__(256) void gather_mean_bf512(
    const unsigned short* __restrict__ xb, const int* __restrict__ row_ptr,
    const int* __restrict__ csr_src, unsigned short* __restrict__ aggb)
{
  const int node = blockIdx.x * 4 + (threadIdx.x >> 6);
  const int t = threadIdx.x & 63;
  if (node >= M_PAD) return;
  if (node >= N_NODES) {                // zero pad rows (ws is not re-zeroed between replays)
    *reinterpret_cast<uint4*>(aggb + (size_t)node * 512 + t * 8) = make_uint4(0, 0, 0, 0);
    return;
  }
  const int beg = row_ptr[node];
  const int end = row_ptr[node + 1];
  float acc[8] = {0.f, 0.f, 0.f, 0.f, 0.f, 0.f, 0.f, 0.f};
  for (int j = beg; j < end; j += 8) {
    uint4 v[8];
    float m[8];
#pragma unroll
    for (int u = 0; u < 8; ++u) {
      const int e = min(j + u, end - 1);
      m[u] = (j + u < end) ? 1.0f : 0.0f;
      v[u] = *reinterpret_cast<const uint4*>(xb + (size_t)csr_src[e] * 512 + t * 8);
    }
#pragma unroll
    for (int u = 0; u < 8; ++u) {
      const unsigned int w[4] = {v[u].x, v[u].y, v[u].z, v[u].w};
#pragma unroll
      for (int q = 0; q < 4; ++q) {
        acc[2 * q]     = fmaf(m[u], b2f((unsigned short)(w[q] & 0xFFFF)), acc[2 * q]);
        acc[2 * q + 1] = fmaf(m[u], b2f((unsigned short)(w[q] >> 16)),    acc[2 * q + 1]);
      }
    }
  }
  const int deg = end - beg;
  const float inv = 1.0f / (float)(deg > 1 ? deg : 1);
  unsigned short r[8];
#pragma unroll
  for (int q = 0; q < 8; ++q) r[q] = f2b(acc[q] * inv);
  *reinterpret_cast<uint4*>(aggb + (size_t)node * 512 + t * 8) = *reinterpret_cast<const uint4*>(r);
}

// ---------------- 128x128 4-wave bf16 MFMA GEMM (single-buffer; settled best) ----------------
// niter=16: C = A1@B1.T + A2@B2.T (K=512 each);  niter=8: C = A1@B1.T.
__global__ __launch_bounds__(256) void gemm_mfma(
    const unsigned short* __restrict__ A1, const unsigned short* __restrict__ A2,
    const unsigned short* __restrict__ B1, const unsigned short* __restrict__ B2,
    const float* __restrict__ bias, unsigned short* __restrict__ Cout,
    int J, int niter, int fuse, int relu)
{
  __shared__ __align__(16) unsigned short Alds[128 * 64];
  __shared__ __align__(16) unsigned short Blds[128 * 64];
  const int tid = threadIdx.x;
  const int lane = tid & 63;
  const int wid = tid >> 6;          // 4 waves

  // XCD chunk swizzle over col-major flatten (nwg % 8 == 0: 2792/1396 for our shapes)
  const int nwg = gridDim.x * gridDim.y;
  int wg = blockIdx.y * gridDim.x + blockIdx.x;
  const int cpx = nwg >> 3;
  wg = (wg & 7) * cpx + (wg >> 3);
  const int brow = (wg / gridDim.y) * 128;   // consecutive wg on an XCD share the A row-panel
  const int bcol = (wg % gridDim.y) * 128;

  const int wr = wid >> 1;           // wave's 64x64 quadrant
  const int wc = wid & 1;

  f32x4 acc[4][4];
#pragma unroll
  for (int m = 0; m < 4; ++m)
#pragma unroll
    for (int n = 0; n < 4; ++n) acc[m][n] = (f32x4){0.f, 0.f, 0.f, 0.f};

  const int srow = lane >> 3;            // 0..7: row within 8-row stripe
  const int schunk = (lane & 7) ^ srow;  // T2: pre-swizzled source 16B-chunk (rule 21)
  const int fr = lane & 15;              // fragment row/col
  const int fk = lane >> 4;              // fragment k-group (8 elems)

  for (int it = 0; it < niter; ++it) {
    const unsigned short* __restrict__ A = (it < 8) ? A1 : A2;
    const unsigned short* __restrict__ B = (it < 8) ? B1 : B2;
    const int k0 = (it & 7) * 64;
    __syncthreads();                 // previous tile's reads done before overwrite
#pragma unroll
    for (int i = 0; i < 4; ++i) {
      const int rbase = i * 32 + wid * 8;   // wave-uniform 8-row stripe
      const int row = rbase + srow;
      __builtin_amdgcn_global_load_lds(
          (const __attribute__((address_space(1))) unsigned int*)(A + (size_t)(brow + row) * KP + k0 + schunk * 8),
          (__attribute__((address_space(3))) unsigned int*)(&Alds[rbase * 64]),
          16, 0, 0);
      __builtin_amdgcn_global_load_lds(
          (const __attribute__((address_space(1))) unsigned int*)(B + (size_t)(bcol + row) * KP + k0 + schunk * 8),
          (__attribute__((address_space(3))) unsigned int*)(&Blds[rbase * 64]),
          16, 0, 0);
    }
    __syncthreads();                 // staging visible (compiler drains vmcnt)
#pragma unroll
    for (int ks = 0; ks < 2; ++ks) {
      bf16x8 a[4], b[4];
#pragma unroll
      for (int m = 0; m < 4; ++m) {
        const int row = wr * 64 + m * 16 + fr;
        a[m] = *reinterpret_cast<const bf16x8*>(&Alds[row * 64 + (((ks * 4 + fk) ^ (row & 7)) * 8)]);
      }
#pragma unroll
      for (int n = 0; n < 4; ++n) {
        const int row = wc * 64 + n * 16 + fr;
        b[n] = *reinterpret_cast<const bf16x8*>(&Blds[row * 64 + (((ks * 4 + fk) ^ (row & 7)) * 8)]);
      }
#pragma unroll
      for (int m = 0; m < 4; ++m)
#pragma unroll
        for (int n = 0; n < 4; ++n)
          acc[m][n] = __builtin_amdgcn_mfma_f32_16x16x32_bf16(a[m], b[n], acc[m][n], 0, 0, 0);
    }
  }

  // epilogue: C/D layout col=lane&15, row=(lane>>4)*4+i  [m89-verified]
  const int crow0 = brow + wr * 64 + (lane >> 4) * 4;
  const int ccol0 = bcol + wc * 64 + (lane & 15);
#pragma unroll
  for (int n = 0; n < 4; ++n) {
    const int col = ccol0 + n * 16;
    const float bv = fuse ? bias[col] : 0.0f;
#pragma unroll
    for (int m = 0; m < 4; ++m) {
#pragma unroll
      for (int i = 0; i < 4; ++i) {
        const int row = crow0 + m * 16 + i;
        float v = acc[m][n][i] + bv;
        if (relu) v = fmaxf(v, 0.0f);
        Cout[(size_t)row * J + col] = f2b(v);
      }
    }
  }
}

// ---------------- fused layer-2 combine + layer-3 projection ----------------
__global__ __launch_bounds__(256) void combine2p3_kernel(
    const unsigned short* __restrict__ y, const int* __restrict__ row_ptr,
    const int* __restrict__ csr_src, const float* __restrict__ bias,
    const unsigned short* __restrict__ w3b, unsigned short* __restrict__ y3)
{
  __shared__ unsigned short w3s[16 * 256];
  {
    const int t0 = threadIdx.x * 16;
    *reinterpret_cast<uint4*>(&w3s[t0])     = *reinterpret_cast<const uint4*>(&w3b[t0]);
    *reinterpret_cast<uint4*>(&w3s[t0 + 8]) = *reinterpret_cast<const uint4*>(&w3b[t0 + 8]);
  }
  __syncthreads();

  const int node = blockIdx.x * 8 + (threadIdx.x >> 5);
  const int t = threadIdx.x & 31;        // 8 channels each -> 256
  if (node >= N_NODES) return;
  const int beg = row_ptr[node];
  const int end = row_ptr[node + 1];
  float acc[8] = {0.f, 0.f, 0.f, 0.f, 0.f, 0.f, 0.f, 0.f};
  for (int j = beg; j < end; j += 8) {
    uint4 v[8];
    float m[8];
#pragma unroll
    for (int u = 0; u < 8; ++u) {
      const int e = min(j + u, end - 1);
      m[u] = (j + u < end) ? 1.0f : 0.0f;
      v[u] = *reinterpret_cast<const uint4*>(y + (size_t)csr_src[e] * 512 + t * 8);
    }
#pragma unroll
    for (int u = 0; u < 8; ++u) {
      const unsigned int w[4] = {v[u].x, v[u].y, v[u].z, v[u].w};
#pragma unroll
      for (int q = 0; q < 4; ++q) {
        acc[2 * q]     = fmaf(m[u], b2f((unsigned short)(w[q] & 0xFFFF)), acc[2 * q]);
        acc[2 * q + 1] = fmaf(m[u], b2f((unsigned short)(w[q] >> 16)),    acc[2 * q + 1]);
      }
    }
  }
  const int deg = end - beg;
  const float inv = 1.0f / (float)(deg > 1 ? deg : 1);
  const uint4 rv = *reinterpret_cast<const uint4*>(y + (size_t)node * 512 + 256 + t * 8);
  const unsigned int ru[4] = {rv.x, rv.y, rv.z, rv.w};
  float c[8];
#pragma unroll
  for (int q = 0; q < 4; ++q) {
    const float y0 = b2f((unsigned short)(ru[q] & 0xFFFF));
    const float y1 = b2f((unsigned short)(ru[q] >> 16));
    c[2 * q]     = fmaxf(acc[2 * q] * inv + y0 + bias[t * 8 + 2 * q], 0.0f);
    c[2 * q + 1] = fmaxf(acc[2 * q + 1] * inv + y1 + bias[t * 8 + 2 * q + 1], 0.0f);
  }
#pragma unroll
  for (int jj = 0; jj < 14; ++jj) {
    const int row = jj + (jj >= 7 ? 1 : 0);      // skip padding rows 7/15
    const uint4 wv = *reinterpret_cast<const uint4*>(&w3s[row * 256 + t * 8]);
    const unsigned int wu[4] = {wv.x, wv.y, wv.z, wv.w};
    float s = 0.0f;
#pragma unroll
    for (int q = 0; q < 4; ++q) {
      s = fmaf(c[2 * q],     b2f((unsigned short)(wu[q] & 0xFFFF)), s);
      s = fmaf(c[2 * q + 1], b2f((unsigned short)(wu[q] >> 16)),    s);
    }
#pragma unroll
    for (int m = 1; m < 32; m <<= 1) s += __shfl_xor(s, m, 64);
    if (t == 0) y3[(size_t)node * 16 + row] = f2b(s);
  }
}

// ---------------- combine layer 3: out = mean-gather(y3[:, 0..6]) + y3[i, 8..14] + b3 ----------------
__global__ __launch_bounds__(256) void combine3_kernel(
    const unsigned short* __restrict__ y3, const int* __restrict__ row_ptr,
    const int* __restrict__ csr_src, const float* __restrict__ b3,
    float* __restrict__ out, int N)
{
  const int node = blockIdx.x * 4 + (threadIdx.x >> 6);
  const int lane = threadIdx.x & 63;
  if (node >= N) return;
  const int beg = row_ptr[node];
  const int end = row_ptr[node + 1];
  float acc[7] = {0.f, 0.f, 0.f, 0.f, 0.f, 0.f, 0.f};
  for (int j = beg + lane; j < end; j += 64) {
    const int s = csr_src[j];
    const uint4 v = *reinterpret_cast<const uint4*>(y3 + (size_t)s * 16);
    const unsigned int u[4] = {v.x, v.y, v.z, v.w};
#pragma unroll
    for (int q = 0; q < 7; ++q) {
      const unsigned short hw = (unsigned short)((u[q >> 1] >> ((q & 1) * 16)) & 0xFFFF);
      acc[q] += b2f(hw);
    }
  }
#pragma unroll
  for (int q = 0; q < 7; ++q)
#pragma unroll
    for (int m = 1; m < 64; m <<= 1)
      acc[q] += __shfl_xor(acc[q], m, 64);
  if (lane == 0) {
    const int deg = end - beg;
    const float inv = 1.0f / (float)(deg > 1 ? deg : 1);
    const uint4 rv = *reinterpret_cast<const uint4*>(y3 + (size_t)node * 16 + 8);
    const unsigned int ru[4] = {rv.x, rv.y, rv.z, rv.w};
#pragma unroll
    for (int q = 0; q < 7; ++q) {
      const float self = b2f((unsigned short)((ru[q >> 1] >> ((q & 1) * 16)) & 0xFFFF));
      out[(size_t)node * F3 + q] = acc[q] * inv + self + b3[q];
    }
  }
}

extern "C" void kernel_launch(void* const* d_in, const int* in_sizes, int n_in,
                              void* d_out, int out_size, void* d_ws, size_t ws_size,
                              hipStream_t stream) {
  const float* x    = (const float*)d_in[0];
  const int*   ei   = (const int*)d_in[1];
  const float* w_l1 = (const float*)d_in[2];
  const float* w_r1 = (const float*)d_in[3];
  const float* b1   = (const float*)d_in[4];
  const float* w_l2 = (const float*)d_in[5];
  const float* w_r2 = (const float*)d_in[6];
  const float* b2   = (const float*)d_in[7];
  const float* w_l3 = (const float*)d_in[8];
  const float* w_r3 = (const float*)d_in[9];
  const float* b3   = (const float*)d_in[10];
  float* out = (float*)d_out;

  const int E = in_sizes[1] / 2;
  const int* src = ei;
  const int* dst = ei + E;

  // ---- workspace carve-up
  char* p = (char*)d_ws;
  int* row_ptr = (int*)p;           p += (size_t)(N_NODES + 1) * 4;
  int* cnt     = (int*)p;           p += (size_t)N_NODES * 4;
  int* bsum    = (int*)p;           p += 1024 * 4;
  int* csr_src = (int*)p;           p += (size_t)E * 4;
  p = (char*)(((uintptr_t)p + 255) & ~(uintptr_t)255);
  unsigned short* xb   = (unsigned short*)p;  p += (size_t)M_PAD * KP * 2;  // also reused as y2
  unsigned short* aggb = (unsigned short*)p;  p += (size_t)M_PAD * KP * 2;
  unsigned short* h1b  = (unsigned short*)p;  p += (size_t)M_PAD * KP * 2;  // also reused as y3
  unsigned short* wl1b = (unsigned short*)p;  p += (size_t)F1 * KP * 2;
  unsigned short* wr1b = (unsigned short*)p;  p += (size_t)F1 * KP * 2;
  unsigned short* w2b  = (unsigned short*)p;  p += (size_t)F1 * KP * 2;     // concat [wl2; wr2] -> 512 rows
  unsigned short* w3b  = (unsigned short*)p;  p += (size_t)16 * F2 * 2;     // [16,256]

  unsigned short* y2  = xb;     // [M_PAD, 512]; xb dead after GEMM1
  unsigned short* y3  = h1b;    // [M_PAD, 16];  h1b dead after GEMM2

  const int nb = cdiv_i(N_NODES, 1024);   // 88

  // ---- CSR build
  hipMemsetAsync(cnt, 0, (size_t)N_NODES * sizeof(int), stream);
  degree_kernel<<<cdiv_i(E, 256), 256, 0, stream>>>(dst, cnt, E);
  scan_partial<<<nb, 1024, 0, stream>>>(cnt, row_ptr, bsum, N_NODES);
  scan_bsums<<<1, 1024, 0, stream>>>(bsum, nb);
  scan_add<<<nb, 1024, 0, stream>>>(row_ptr, bsum, cnt, N_NODES, E);   // cnt becomes cursor
  fill_kernel<<<cdiv_i(E, 256), 256, 0, stream>>>(src, dst, cnt, csr_src, E);

  // ---- conversions (x + all weights, one kernel)
  {
    const int wblocks = cdiv_i(F1 * KP + F2 * KP + 16 * F2, 256);   // 1552
    prep_kernel<<<XBLK + wblocks, 256, 0, stream>>>(
        x, w_l1, w_r1, w_l2, w_r2, w_l3, w_r3, xb, wl1b, wr1b, w2b, w3b);
  }

  // ---- layer 1: agg = mean-gather(x);  h1 = relu(agg@wl1.T + x@wr1.T + b1)
  gather_mean_bf512<<<cdiv_i(M_PAD, 4), 256, 0, stream>>>(xb, row_ptr, csr_src, aggb);
  {
    dim3 g(M_PAD / 128, F1 / 128);
    gemm_mfma<<<g, 256, 0, stream>>>(aggb, xb, wl1b, wr1b, b1, h1b, F1, 16, 1, 1);
  }

  // ---- layer 2 (aggregate AFTER projection): y2 = h1 @ [wl2; wr2].T
  {
    dim3 g(M_PAD / 128, 512 / 128);
    gemm_mfma<<<g, 256, 0, stream>>>(h1b, h1b, w2b, w2b, (const float*)nullptr, y2, 512, 8, 0, 0);
  }
  // fused: combine layer 2 + project layer 3 (h2 never materialized)
  combine2p3_kernel<<<cdiv_i(N_NODES, 8), 256, 0, stream>>>(y2, row_ptr, csr_src, b2, w3b, y3);

  // ---- combine layer 3
  combine3_kernel<<<cdiv_i(N_NODES, 4), 256, 0, stream>>>(y3, row_ptr, csr_src, b3, out, N_NODES);
}

// Round 12
// 597.416 us; speedup vs baseline: 1.1232x; 1.1008x over previous
//
#include <hip/hip_runtime.h>
#include <cstdint>
#include <cstddef>

#define N_NODES 89250
#define M_PAD   89344   // 698 * 128
#define F0 500
#define F1 512
#define F2 256
#define F3 7
#define KP 512          // padded K for the MFMA GEMMs

typedef __attribute__((ext_vector_type(8))) short bf16x8;   // 8 bf16 = 4 VGPRs
typedef __attribute__((ext_vector_type(4))) float f32x4;

static inline int cdiv_i(int a, int b) { return (a + b - 1) / b; }

__device__ __forceinline__ unsigned short f2b(float f) {
  unsigned int u = __float_as_uint(f);
  u = (u + 0x7FFFu + ((u >> 16) & 1u)) >> 16;
  return (unsigned short)u;
}
__device__ __forceinline__ float b2f(unsigned short h) {
  return __uint_as_float(((unsigned int)h) << 16);
}
__device__ __forceinline__ uint4 pack8(const float* v) {
  unsigned short r[8];
#pragma unroll
  for (int j = 0; j < 8; ++j) r[j] = f2b(v[j]);
  return *reinterpret_cast<const uint4*>(r);
}

// ---------------- CSR build ----------------
__global__ void degree_kernel(const int* __restrict__ dst, int* __restrict__ cnt, int E) {
  int stride = gridDim.x * blockDim.x;
  for (int i = blockIdx.x * blockDim.x + threadIdx.x; i < E; i += stride)
    atomicAdd(&cnt[dst[i]], 1);
}

__global__ __launch_bounds__(1024) void scan_partial(const int* __restrict__ cnt,
                                                     int* __restrict__ row_ptr,
                                                     int* __restrict__ bsum, int n) {
  __shared__ int sm[1024];
  const int i = blockIdx.x * 1024 + threadIdx.x;
  const int v = (i < n) ? cnt[i] : 0;
  sm[threadIdx.x] = v;
  __syncthreads();
  for (int off = 1; off < 1024; off <<= 1) {
    int t = (threadIdx.x >= off) ? sm[threadIdx.x - off] : 0;
    __syncthreads();
    sm[threadIdx.x] += t;
    __syncthreads();
  }
  if (i < n) row_ptr[i] = sm[threadIdx.x] - v;    // block-local exclusive
  if (threadIdx.x == 1023) bsum[blockIdx.x] = sm[1023];
}

__global__ __launch_bounds__(1024) void scan_bsums(int* __restrict__ bsum, int nb) {
  __shared__ int sm[1024];
  const int v = (threadIdx.x < nb) ? bsum[threadIdx.x] : 0;
  sm[threadIdx.x] = v;
  __syncthreads();
  for (int off = 1; off < 1024; off <<= 1) {
    int t = (threadIdx.x >= off) ? sm[threadIdx.x - off] : 0;
    __syncthreads();
    sm[threadIdx.x] += t;
    __syncthreads();
  }
  if (threadIdx.x < nb) bsum[threadIdx.x] = sm[threadIdx.x] - v;  // exclusive
}

// adds block offsets AND initializes cursor = row_ptr (saves a pass)
__global__ __launch_bounds__(1024) void scan_add(int* __restrict__ row_ptr,
                                                 const int* __restrict__ bsum,
                                                 int* __restrict__ cursor,
                                                 int n, int total) {
  const int i = blockIdx.x * 1024 + threadIdx.x;
  if (i < n) {
    const int v = row_ptr[i] + bsum[i >> 10];
    row_ptr[i] = v;
    cursor[i] = v;
  }
  if (i == 0) row_ptr[n] = total;
}

__global__ void fill_kernel(const int* __restrict__ src, const int* __restrict__ dst,
                            int* __restrict__ cursor, int* __restrict__ csr_src, int E) {
  int stride = gridDim.x * blockDim.x;
  for (int i = blockIdx.x * blockDim.x + threadIdx.x; i < E; i += stride) {
    const int p = atomicAdd(&cursor[dst[i]], 1);
    csr_src[p] = src[i];
  }
}

// ---------------- fused conversion: x + all weights, float4-vectorized ----------------
// row length 500 floats: byte offset 2000*row + 4*c8 with c8 % 8 == 0 -> 16B aligned.
#define XBLK (M_PAD * 64 / 256)     // 22336
#define W1BLK 128                   // 512 rows x 64 granules / 256
#define W2BLK 128                   // 131072 floats / 4 / 256
__global__ __launch_bounds__(256) void prep_kernel(
    const float* __restrict__ x,
    const float* __restrict__ wl1, const float* __restrict__ wr1,
    const float* __restrict__ wl2, const float* __restrict__ wr2,
    const float* __restrict__ wl3, const float* __restrict__ wr3,
    unsigned short* __restrict__ xb,
    unsigned short* __restrict__ wl1b, unsigned short* __restrict__ wr1b,
    unsigned short* __restrict__ w2b, unsigned short* __restrict__ w3b)
{
  int b = blockIdx.x;
  if (b < XBLK) {
    const int idx = b * 256 + threadIdx.x;
    const int node = idx >> 6;
    const int c8 = (idx & 63) * 8;
    float v[8] = {0.f, 0.f, 0.f, 0.f, 0.f, 0.f, 0.f, 0.f};
    if (node < N_NODES) {
      const float* xr = x + (size_t)node * F0;
      if (c8 + 8 <= F0) {
        const float4 a = *reinterpret_cast<const float4*>(xr + c8);
        const float4 d = *reinterpret_cast<const float4*>(xr + c8 + 4);
        v[0] = a.x; v[1] = a.y; v[2] = a.z; v[3] = a.w;
        v[4] = d.x; v[5] = d.y; v[6] = d.z; v[7] = d.w;
      } else if (c8 < F0) {            // c8 == 496: 4 valid cols
        const float4 a = *reinterpret_cast<const float4*>(xr + c8);
        v[0] = a.x; v[1] = a.y; v[2] = a.z; v[3] = a.w;
      }
    }
    *reinterpret_cast<uint4*>(xb + (size_t)node * KP + c8) = pack8(v);
    return;
  }
  b -= XBLK;
  if (b < W1BLK) {                     // wl1 + wr1: [512,500] -> [512,512]
    const int idx = b * 256 + threadIdx.x;   // 0..32767
    const int j = idx >> 6;
    const int c8 = (idx & 63) * 8;
    float vl[8] = {0.f, 0.f, 0.f, 0.f, 0.f, 0.f, 0.f, 0.f};
    float vr[8] = {0.f, 0.f, 0.f, 0.f, 0.f, 0.f, 0.f, 0.f};
    const float* lr = wl1 + (size_t)j * F0;
    const float* rr = wr1 + (size_t)j * F0;
    if (c8 + 8 <= F0) {
      const float4 a = *reinterpret_cast<const float4*>(lr + c8);
      const float4 d = *reinterpret_cast<const float4*>(lr + c8 + 4);
      vl[0] = a.x; vl[1] = a.y; vl[2] = a.z; vl[3] = a.w;
      vl[4] = d.x; vl[5] = d.y; vl[6] = d.z; vl[7] = d.w;
      const float4 e = *reinterpret_cast<const float4*>(rr + c8);
      const float4 f = *reinterpret_cast<const float4*>(rr + c8 + 4);
      vr[0] = e.x; vr[1] = e.y; vr[2] = e.z; vr[3] = e.w;
      vr[4] = f.x; vr[5] = f.y; vr[6] = f.z; vr[7] = f.w;
    } else if (c8 < F0) {              // c8 == 496
      const float4 a = *reinterpret_cast<const float4*>(lr + c8);
      vl[0] = a.x; vl[1] = a.y; vl[2] = a.z; vl[3] = a.w;
      const float4 e = *reinterpret_cast<const float4*>(rr + c8);
      vr[0] = e.x; vr[1] = e.y; vr[2] = e.z; vr[3] = e.w;
    }
    *reinterpret_cast<uint4*>(wl1b + (size_t)j * KP + c8) = pack8(vl);
    *reinterpret_cast<uint4*>(wr1b + (size_t)j * KP + c8) = pack8(vr);
    return;
  }
  b -= W1BLK;
  const int S2 = F2 * KP;              // 131072
  if (b < W2BLK) {                     // wl2 / wr2: fully contiguous
    const int off = (b * 256 + threadIdx.x) * 4;
    const float4 a = *reinterpret_cast<const float4*>(wl2 + off);
    const float4 d = *reinterpret_cast<const float4*>(wr2 + off);
    unsigned short rl[4] = {f2b(a.x), f2b(a.y), f2b(a.z), f2b(a.w)};
    unsigned short rrr[4] = {f2b(d.x), f2b(d.y), f2b(d.z), f2b(d.w)};
    *reinterpret_cast<uint2*>(w2b + off)      = *reinterpret_cast<const uint2*>(rl);
    *reinterpret_cast<uint2*>(w2b + S2 + off) = *reinterpret_cast<const uint2*>(rrr);
    return;
  }
  b -= W2BLK;
  {                                    // w3b [16,256]: rows 0..6 wl3, 8..14 wr3
    const int idx = b * 256 + threadIdx.x;
    if (idx < 16 * 256) {
      const int j = idx >> 8, k = idx & 255;
      float v = 0.0f;
      if (j < 7) v = wl3[(size_t)j * F2 + k];
      else if (j >= 8 && j < 15) v = wr3[(size_t)(j - 8) * F2 + k];
      w3b[idx] = f2b(v);
    }
  }
}

// ---------------- gather-mean (bf16 in/out, f32 accum), C=512, wave per node ----------------
__global__ __launch_bounds__(256) void gather_mean_bf512(
    const unsigned short* __restrict__ xb, const int* __restrict__ row_ptr,
    const int* __restrict__ csr_src, unsigned short* __restrict__ aggb)
{
  const int node = blockIdx.x * 4 + (threadIdx.x >> 6);
  const int t = threadIdx.x & 63;
  if (node >= M_PAD) return;
  if (node >= N_NODES) {                // zero pad rows (deterministic)
    *reinterpret_cast<uint4*>(aggb + (size_t)node * 512 + t * 8) = make_uint4(0, 0, 0, 0);
    return;
  }
  const int beg = row_ptr[node];
  const int end = row_ptr[node + 1];
  float acc[8] = {0.f, 0.f, 0.f, 0.f, 0.f, 0.f, 0.f, 0.f};
  for (int j = beg; j < end; j += 8) {
    uint4 v[8];
    float m[8];
#pragma unroll
    for (int u = 0; u < 8; ++u) {
      const int e = min(j + u, end - 1);
      m[u] = (j + u < end) ? 1.0f : 0.0f;
      v[u] = *reinterpret_cast<const uint4*>(xb + (size_t)csr_src[e] * 512 + t * 8);
    }
#pragma unroll
    for (int u = 0; u < 8; ++u) {
      const unsigned int w[4] = {v[u].x, v[u].y, v[u].z, v[u].w};
#pragma unroll
      for (int q = 0; q < 4; ++q) {
        acc[2 * q]     = fmaf(m[u], b2f((unsigned short)(w[q] & 0xFFFF)), acc[2 * q]);
        acc[2 * q + 1] = fmaf(m[u], b2f((unsigned short)(w[q] >> 16)),    acc[2 * q + 1]);
      }
    }
  }
  const int deg = end - beg;
  const float inv = 1.0f / (float)(deg > 1 ? deg : 1);
  unsigned short r[8];
#pragma unroll
  for (int q = 0; q < 8; ++q) r[q] = f2b(acc[q] * inv);
  *reinterpret_cast<uint4*>(aggb + (size_t)node * 512 + t * 8) = *reinterpret_cast<const uint4*>(r);
}

// ---------------- 128x128 4-wave bf16 MFMA GEMM (single-buffer; settled best) ----------------
// niter=16: C = A1@B1.T + A2@B2.T (K=512 each);  niter=8: C = A1@B1.T.
__global__ __launch_bounds__(256) void gemm_mfma(
    const unsigned short* __restrict__ A1, const unsigned short* __restrict__ A2,
    const unsigned short* __restrict__ B1, const unsigned short* __restrict__ B2,
    const float* __restrict__ bias, unsigned short* __restrict__ Cout,
    int J, int niter, int fuse, int relu)
{
  __shared__ __align__(16) unsigned short Alds[128 * 64];
  __shared__ __align__(16) unsigned short Blds[128 * 64];
  const int tid = threadIdx.x;
  const int lane = tid & 63;
  const int wid = tid >> 6;          // 4 waves

  // XCD chunk swizzle over col-major flatten (nwg % 8 == 0: 2792/1396 for our shapes)
  const int nwg = gridDim.x * gridDim.y;
  int wg = blockIdx.y * gridDim.x + blockIdx.x;
  const int cpx = nwg >> 3;
  wg = (wg & 7) * cpx + (wg >> 3);
  const int brow = (wg / gridDim.y) * 128;   // consecutive wg on an XCD share the A row-panel
  const int bcol = (wg % gridDim.y) * 128;

  const int wr = wid >> 1;           // wave's 64x64 quadrant
  const int wc = wid & 1;

  f32x4 acc[4][4];
#pragma unroll
  for (int m = 0; m < 4; ++m)
#pragma unroll
    for (int n = 0; n < 4; ++n) acc[m][n] = (f32x4){0.f, 0.f, 0.f, 0.f};

  const int srow = lane >> 3;            // 0..7: row within 8-row stripe
  const int schunk = (lane & 7) ^ srow;  // T2: pre-swizzled source 16B-chunk (rule 21)
  const int fr = lane & 15;              // fragment row/col
  const int fk = lane >> 4;              // fragment k-group (8 elems)

  for (int it = 0; it < niter; ++it) {
    const unsigned short* __restrict__ A = (it < 8) ? A1 : A2;
    const unsigned short* __restrict__ B = (it < 8) ? B1 : B2;
    const int k0 = (it & 7) * 64;
    __syncthreads();                 // previous tile's reads done before overwrite
#pragma unroll
    for (int i = 0; i < 4; ++i) {
      const int rbase = i * 32 + wid * 8;   // wave-uniform 8-row stripe
      const int row = rbase + srow;
      __builtin_amdgcn_global_load_lds(
          (const __attribute__((address_space(1))) unsigned int*)(A + (size_t)(brow + row) * KP + k0 + schunk * 8),
          (__attribute__((address_space(3))) unsigned int*)(&Alds[rbase * 64]),
          16, 0, 0);
      __builtin_amdgcn_global_load_lds(
          (const __attribute__((address_space(1))) unsigned int*)(B + (size_t)(bcol + row) * KP + k0 + schunk * 8),
          (__attribute__((address_space(3))) unsigned int*)(&Blds[rbase * 64]),
          16, 0, 0);
    }
    __syncthreads();                 // staging visible (compiler drains vmcnt)
#pragma unroll
    for (int ks = 0; ks < 2; ++ks) {
      bf16x8 a[4], b[4];
#pragma unroll
      for (int m = 0; m < 4; ++m) {
        const int row = wr * 64 + m * 16 + fr;
        a[m] = *reinterpret_cast<const bf16x8*>(&Alds[row * 64 + (((ks * 4 + fk) ^ (row & 7)) * 8)]);
      }
#pragma unroll
      for (int n = 0; n < 4; ++n) {
        const int row = wc * 64 + n * 16 + fr;
        b[n] = *reinterpret_cast<const bf16x8*>(&Blds[row * 64 + (((ks * 4 + fk) ^ (row & 7)) * 8)]);
      }
#pragma unroll
      for (int m = 0; m < 4; ++m)
#pragma unroll
        for (int n = 0; n < 4; ++n)
          acc[m][n] = __builtin_amdgcn_mfma_f32_16x16x32_bf16(a[m], b[n], acc[m][n], 0, 0, 0);
    }
  }

  // epilogue: C/D layout col=lane&15, row=(lane>>4)*4+i  [m89-verified]
  const int crow0 = brow + wr * 64 + (lane >> 4) * 4;
  const int ccol0 = bcol + wc * 64 + (lane & 15);
#pragma unroll
  for (int n = 0; n < 4; ++n) {
    const int col = ccol0 + n * 16;
    const float bv = fuse ? bias[col] : 0.0f;
#pragma unroll
    for (int m = 0; m < 4; ++m) {
#pragma unroll
      for (int i = 0; i < 4; ++i) {
        const int row = crow0 + m * 16 + i;
        float v = acc[m][n][i] + bv;
        if (relu) v = fmaxf(v, 0.0f);
        Cout[(size_t)row * J + col] = f2b(v);
      }
    }
  }
}

// ---------------- fused layer-2 combine + layer-3 projection ----------------
__global__ __launch_bounds__(256) void combine2p3_kernel(
    const unsigned short* __restrict__ y, const int* __restrict__ row_ptr,
    const int* __restrict__ csr_src, const float* __restrict__ bias,
    const unsigned short* __restrict__ w3b, unsigned short* __restrict__ y3)
{
  __shared__ unsigned short w3s[16 * 256];
  {
    const int t0 = threadIdx.x * 16;
    *reinterpret_cast<uint4*>(&w3s[t0])     = *reinterpret_cast<const uint4*>(&w3b[t0]);
    *reinterpret_cast<uint4*>(&w3s[t0 + 8]) = *reinterpret_cast<const uint4*>(&w3b[t0 + 8]);
  }
  __syncthreads();

  const int node = blockIdx.x * 8 + (threadIdx.x >> 5);
  const int t = threadIdx.x & 31;        // 8 channels each -> 256
  if (node >= N_NODES) return;
  const int beg = row_ptr[node];
  const int end = row_ptr[node + 1];
  float acc[8] = {0.f, 0.f, 0.f, 0.f, 0.f, 0.f, 0.f, 0.f};
  for (int j = beg; j < end; j += 8) {
    uint4 v[8];
    float m[8];
#pragma unroll
    for (int u = 0; u < 8; ++u) {
      const int e = min(j + u, end - 1);
      m[u] = (j + u < end) ? 1.0f : 0.0f;
      v[u] = *reinterpret_cast<const uint4*>(y + (size_t)csr_src[e] * 512 + t * 8);
    }
#pragma unroll
    for (int u = 0; u < 8; ++u) {
      const unsigned int w[4] = {v[u].x, v[u].y, v[u].z, v[u].w};
#pragma unroll
      for (int q = 0; q < 4; ++q) {
        acc[2 * q]     = fmaf(m[u], b2f((unsigned short)(w[q] & 0xFFFF)), acc[2 * q]);
        acc[2 * q + 1] = fmaf(m[u], b2f((unsigned short)(w[q] >> 16)),    acc[2 * q + 1]);
      }
    }
  }
  const int deg = end - beg;
  const float inv = 1.0f / (float)(deg > 1 ? deg : 1);
  const uint4 rv = *reinterpret_cast<const uint4*>(y + (size_t)node * 512 + 256 + t * 8);
  const unsigned int ru[4] = {rv.x, rv.y, rv.z, rv.w};
  float c[8];
#pragma unroll
  for (int q = 0; q < 4; ++q) {
    const float y0 = b2f((unsigned short)(ru[q] & 0xFFFF));
    const float y1 = b2f((unsigned short)(ru[q] >> 16));
    c[2 * q]     = fmaxf(acc[2 * q] * inv + y0 + bias[t * 8 + 2 * q], 0.0f);
    c[2 * q + 1] = fmaxf(acc[2 * q + 1] * inv + y1 + bias[t * 8 + 2 * q + 1], 0.0f);
  }
#pragma unroll
  for (int jj = 0; jj < 14; ++jj) {
    const int row = jj + (jj >= 7 ? 1 : 0);      // skip padding rows 7/15
    const uint4 wv = *reinterpret_cast<const uint4*>(&w3s[row * 256 + t * 8]);
    const unsigned int wu[4] = {wv.x, wv.y, wv.z, wv.w};
    float s = 0.0f;
#pragma unroll
    for (int q = 0; q < 4; ++q) {
      s = fmaf(c[2 * q],     b2f((unsigned short)(wu[q] & 0xFFFF)), s);
      s = fmaf(c[2 * q + 1], b2f((unsigned short)(wu[q] >> 16)),    s);
    }
#pragma unroll
    for (int m = 1; m < 32; m <<= 1) s += __shfl_xor(s, m, 64);
    if (t == 0) y3[(size_t)node * 16 + row] = f2b(s);
  }
}

// ---------------- combine layer 3: out = mean-gather(y3[:, 0..6]) + y3[i, 8..14] + b3 ----------------
__global__ __launch_bounds__(256) void combine3_kernel(
    const unsigned short* __restrict__ y3, const int* __restrict__ row_ptr,
    const int* __restrict__ csr_src, const float* __restrict__ b3,
    float* __restrict__ out, int N)
{
  const int node = blockIdx.x * 4 + (threadIdx.x >> 6);
  const int lane = threadIdx.x & 63;
  if (node >= N) return;
  const int beg = row_ptr[node];
  const int end = row_ptr[node + 1];
  float acc[7] = {0.f, 0.f, 0.f, 0.f, 0.f, 0.f, 0.f};
  for (int j = beg + lane; j < end; j += 64) {
    const int s = csr_src[j];
    const uint4 v = *reinterpret_cast<const uint4*>(y3 + (size_t)s * 16);
    const unsigned int u[4] = {v.x, v.y, v.z, v.w};
#pragma unroll
    for (int q = 0; q < 7; ++q) {
      const unsigned short hw = (unsigned short)((u[q >> 1] >> ((q & 1) * 16)) & 0xFFFF);
      acc[q] += b2f(hw);
    }
  }
#pragma unroll
  for (int q = 0; q < 7; ++q)
#pragma unroll
    for (int m = 1; m < 64; m <<= 1)
      acc[q] += __shfl_xor(acc[q], m, 64);
  if (lane == 0) {
    const int deg = end - beg;
    const float inv = 1.0f / (float)(deg > 1 ? deg : 1);
    const uint4 rv = *reinterpret_cast<const uint4*>(y3 + (size_t)node * 16 + 8);
    const unsigned int ru[4] = {rv.x, rv.y, rv.z, rv.w};
#pragma unroll
    for (int q = 0; q < 7; ++q) {
      const float self = b2f((unsigned short)((ru[q >> 1] >> ((q & 1) * 16)) & 0xFFFF));
      out[(size_t)node * F3 + q] = acc[q] * inv + self + b3[q];
    }
  }
}

extern "C" void kernel_launch(void* const* d_in, const int* in_sizes, int n_in,
                              void* d_out, int out_size, void* d_ws, size_t ws_size,
                              hipStream_t stream) {
  const float* x    = (const float*)d_in[0];
  const int*   ei   = (const int*)d_in[1];
  const float* w_l1 = (const float*)d_in[2];
  const float* w_r1 = (const float*)d_in[3];
  const float* b1   = (const float*)d_in[4];
  const float* w_l2 = (const float*)d_in[5];
  const float* w_r2 = (const float*)d_in[6];
  const float* b2   = (const float*)d_in[7];
  const float* w_l3 = (const float*)d_in[8];
  const float* w_r3 = (const float*)d_in[9];
  const float* b3   = (const float*)d_in[10];
  float* out = (float*)d_out;

  const int E = in_sizes[1] / 2;
  const int* src = ei;
  const int* dst = ei + E;

  // ---- workspace carve-up
  char* p = (char*)d_ws;
  int* row_ptr = (int*)p;           p += (size_t)(N_NODES + 1) * 4;
  int* cnt     = (int*)p;           p += (size_t)N_NODES * 4;
  int* bsum    = (int*)p;           p += 1024 * 4;
  int* csr_src = (int*)p;           p += (size_t)E * 4;
  p = (char*)(((uintptr_t)p + 255) & ~(uintptr_t)255);
  unsigned short* xb   = (unsigned short*)p;  p += (size_t)M_PAD * KP * 2;  // also reused as y2
  unsigned short* aggb = (unsigned short*)p;  p += (size_t)M_PAD * KP * 2;
  unsigned short* h1b  = (unsigned short*)p;  p += (size_t)M_PAD * KP * 2;  // also reused as y3
  unsigned short* wl1b = (unsigned short*)p;  p += (size_t)F1 * KP * 2;
  unsigned short* wr1b = (unsigned short*)p;  p += (size_t)F1 * KP * 2;
  unsigned short* w2b  = (unsigned short*)p;  p += (size_t)F1 * KP * 2;     // concat [wl2; wr2] -> 512 rows
  unsigned short* w3b  = (unsigned short*)p;  p += (size_t)16 * F2 * 2;     // [16,256]

  unsigned short* y2  = xb;     // [M_PAD, 512]; xb dead after GEMM1
  unsigned short* y3  = h1b;    // [M_PAD, 16];  h1b dead after GEMM2

  const int nb = cdiv_i(N_NODES, 1024);   // 88

  // ---- CSR build
  hipMemsetAsync(cnt, 0, (size_t)N_NODES * sizeof(int), stream);
  degree_kernel<<<cdiv_i(E, 256), 256, 0, stream>>>(dst, cnt, E);
  scan_partial<<<nb, 1024, 0, stream>>>(cnt, row_ptr, bsum, N_NODES);
  scan_bsums<<<1, 1024, 0, stream>>>(bsum, nb);
  scan_add<<<nb, 1024, 0, stream>>>(row_ptr, bsum, cnt, N_NODES, E);   // cnt becomes cursor
  fill_kernel<<<cdiv_i(E, 256), 256, 0, stream>>>(src, dst, cnt, csr_src, E);

  // ---- conversions (x + all weights, one kernel, float4-vectorized)
  prep_kernel<<<XBLK + W1BLK + W2BLK + 16, 256, 0, stream>>>(
      x, w_l1, w_r1, w_l2, w_r2, w_l3, w_r3, xb, wl1b, wr1b, w2b, w3b);

  // ---- layer 1: agg = mean-gather(x);  h1 = relu(agg@wl1.T + x@wr1.T + b1)
  gather_mean_bf512<<<cdiv_i(M_PAD, 4), 256, 0, stream>>>(xb, row_ptr, csr_src, aggb);
  {
    dim3 g(M_PAD / 128, F1 / 128);
    gemm_mfma<<<g, 256, 0, stream>>>(aggb, xb, wl1b, wr1b, b1, h1b, F1, 16, 1, 1);
  }

  // ---- layer 2 (aggregate AFTER projection): y2 = h1 @ [wl2; wr2].T
  {
    dim3 g(M_PAD / 128, 512 / 128);
    gemm_mfma<<<g, 256, 0, stream>>>(h1b, h1b, w2b, w2b, (const float*)nullptr, y2, 512, 8, 0, 0);
  }
  // fused: combine layer 2 + project layer 3 (h2 never materialized)
  combine2p3_kernel<<<cdiv_i(N_NODES, 8), 256, 0, stream>>>(y2, row_ptr, csr_src, b2, w3b, y3);

  // ---- combine layer 3
  combine3_kernel<<<cdiv_i(N_NODES, 4), 256, 0, stream>>>(y3, row_ptr, csr_src, b3, out, N_NODES);
}

// Round 13
// 595.519 us; speedup vs baseline: 1.1267x; 1.0032x over previous
//
#include <hip/hip_runtime.h>
#include <cstdint>
#include <cstddef>

#define N_NODES 89250
#define M_PAD   89344   // 698 * 128
#define F0 500
#define F1 512
#define F2 256
#define F3 7
#define KP 512          // padded K for the MFMA GEMMs

typedef __attribute__((ext_vector_type(8))) short bf16x8;   // 8 bf16 = 4 VGPRs
typedef __attribute__((ext_vector_type(4))) float f32x4;

static inline int cdiv_i(int a, int b) { return (a + b - 1) / b; }

__device__ __forceinline__ unsigned short f2b(float f) {
  unsigned int u = __float_as_uint(f);
  u = (u + 0x7FFFu + ((u >> 16) & 1u)) >> 16;
  return (unsigned short)u;
}
__device__ __forceinline__ float b2f(unsigned short h) {
  return __uint_as_float(((unsigned int)h) << 16);
}
__device__ __forceinline__ uint4 pack8(const float* v) {
  unsigned short r[8];
#pragma unroll
  for (int j = 0; j < 8; ++j) r[j] = f2b(v[j]);
  return *reinterpret_cast<const uint4*>(r);
}

// ---------------- CSR build (scan) ----------------
__global__ __launch_bounds__(1024) void scan_partial(const int* __restrict__ cnt,
                                                     int* __restrict__ row_ptr,
                                                     int* __restrict__ bsum, int n) {
  __shared__ int sm[1024];
  const int i = blockIdx.x * 1024 + threadIdx.x;
  const int v = (i < n) ? cnt[i] : 0;
  sm[threadIdx.x] = v;
  __syncthreads();
  for (int off = 1; off < 1024; off <<= 1) {
    int t = (threadIdx.x >= off) ? sm[threadIdx.x - off] : 0;
    __syncthreads();
    sm[threadIdx.x] += t;
    __syncthreads();
  }
  if (i < n) row_ptr[i] = sm[threadIdx.x] - v;    // block-local exclusive
  if (threadIdx.x == 1023) bsum[blockIdx.x] = sm[1023];
}

// per-block offset = SUM of bsums before this block (tree reduce), then add + init cursor
__global__ __launch_bounds__(1024) void scan_add_fused(int* __restrict__ row_ptr,
                                                       const int* __restrict__ bsum,
                                                       int* __restrict__ cursor,
                                                       int n, int total, int nb) {
  __shared__ int sb[128];
  const int t = threadIdx.x;
  if (t < 128) sb[t] = (t < nb && t < blockIdx.x) ? bsum[t] : 0;
  __syncthreads();
  for (int off = 64; off >= 1; off >>= 1) {
    if (t < off) sb[t] += sb[t + off];
    __syncthreads();
  }
  const int boff = sb[0];
  const int i = blockIdx.x * 1024 + t;
  if (i < n) {
    const int v = row_ptr[i] + boff;
    row_ptr[i] = v;
    cursor[i] = v;
  }
  if (i == 0) row_ptr[n] = total;
}

__global__ void fill_kernel(const int* __restrict__ src, const int* __restrict__ dst,
                            int* __restrict__ cursor, int* __restrict__ csr_src, int E) {
  int stride = gridDim.x * blockDim.x;
  for (int i = blockIdx.x * blockDim.x + threadIdx.x; i < E; i += stride) {
    const int p = atomicAdd(&cursor[dst[i]], 1);
    csr_src[p] = src[i];
  }
}

// ---------------- fused prep: x + all weights (float4-vectorized) + degree count ----------------
// row length 500 floats: byte offset 2000*row + 4*c8 with c8 % 8 == 0 -> 16B aligned.
#define XBLK (M_PAD * 64 / 256)     // 22336
#define W1BLK 128                   // 512 rows x 64 granules / 256
#define W2BLK 128                   // 131072 floats / 4 / 256
#define W3BLK 16
__global__ __launch_bounds__(256) void prep_kernel(
    const float* __restrict__ x,
    const float* __restrict__ wl1, const float* __restrict__ wr1,
    const float* __restrict__ wl2, const float* __restrict__ wr2,
    const float* __restrict__ wl3, const float* __restrict__ wr3,
    unsigned short* __restrict__ xb,
    unsigned short* __restrict__ wl1b, unsigned short* __restrict__ wr1b,
    unsigned short* __restrict__ w2b, unsigned short* __restrict__ w3b,
    const int* __restrict__ dst, int* __restrict__ cnt, int E)
{
  int b = blockIdx.x;
  if (b < XBLK) {
    const int idx = b * 256 + threadIdx.x;
    const int node = idx >> 6;
    const int c8 = (idx & 63) * 8;
    float v[8] = {0.f, 0.f, 0.f, 0.f, 0.f, 0.f, 0.f, 0.f};
    if (node < N_NODES) {
      const float* xr = x + (size_t)node * F0;
      if (c8 + 8 <= F0) {
        const float4 a = *reinterpret_cast<const float4*>(xr + c8);
        const float4 d = *reinterpret_cast<const float4*>(xr + c8 + 4);
        v[0] = a.x; v[1] = a.y; v[2] = a.z; v[3] = a.w;
        v[4] = d.x; v[5] = d.y; v[6] = d.z; v[7] = d.w;
      } else if (c8 < F0) {            // c8 == 496: 4 valid cols
        const float4 a = *reinterpret_cast<const float4*>(xr + c8);
        v[0] = a.x; v[1] = a.y; v[2] = a.z; v[3] = a.w;
      }
    }
    *reinterpret_cast<uint4*>(xb + (size_t)node * KP + c8) = pack8(v);
    return;
  }
  b -= XBLK;
  if (b < W1BLK) {                     // wl1 + wr1: [512,500] -> [512,512]
    const int idx = b * 256 + threadIdx.x;   // 0..32767
    const int j = idx >> 6;
    const int c8 = (idx & 63) * 8;
    float vl[8] = {0.f, 0.f, 0.f, 0.f, 0.f, 0.f, 0.f, 0.f};
    float vr[8] = {0.f, 0.f, 0.f, 0.f, 0.f, 0.f, 0.f, 0.f};
    const float* lr = wl1 + (size_t)j * F0;
    const float* rr = wr1 + (size_t)j * F0;
    if (c8 + 8 <= F0) {
      const float4 a = *reinterpret_cast<const float4*>(lr + c8);
      const float4 d = *reinterpret_cast<const float4*>(lr + c8 + 4);
      vl[0] = a.x; vl[1] = a.y; vl[2] = a.z; vl[3] = a.w;
      vl[4] = d.x; vl[5] = d.y; vl[6] = d.z; vl[7] = d.w;
      const float4 e = *reinterpret_cast<const float4*>(rr + c8);
      const float4 f = *reinterpret_cast<const float4*>(rr + c8 + 4);
      vr[0] = e.x; vr[1] = e.y; vr[2] = e.z; vr[3] = e.w;
      vr[4] = f.x; vr[5] = f.y; vr[6] = f.z; vr[7] = f.w;
    } else if (c8 < F0) {              // c8 == 496
      const float4 a = *reinterpret_cast<const float4*>(lr + c8);
      vl[0] = a.x; vl[1] = a.y; vl[2] = a.z; vl[3] = a.w;
      const float4 e = *reinterpret_cast<const float4*>(rr + c8);
      vr[0] = e.x; vr[1] = e.y; vr[2] = e.z; vr[3] = e.w;
    }
    *reinterpret_cast<uint4*>(wl1b + (size_t)j * KP + c8) = pack8(vl);
    *reinterpret_cast<uint4*>(wr1b + (size_t)j * KP + c8) = pack8(vr);
    return;
  }
  b -= W1BLK;
  const int S2 = F2 * KP;              // 131072
  if (b < W2BLK) {                     // wl2 / wr2: fully contiguous
    const int off = (b * 256 + threadIdx.x) * 4;
    const float4 a = *reinterpret_cast<const float4*>(wl2 + off);
    const float4 d = *reinterpret_cast<const float4*>(wr2 + off);
    unsigned short rl[4] = {f2b(a.x), f2b(a.y), f2b(a.z), f2b(a.w)};
    unsigned short rrr[4] = {f2b(d.x), f2b(d.y), f2b(d.z), f2b(d.w)};
    *reinterpret_cast<uint2*>(w2b + off)      = *reinterpret_cast<const uint2*>(rl);
    *reinterpret_cast<uint2*>(w2b + S2 + off) = *reinterpret_cast<const uint2*>(rrr);
    return;
  }
  b -= W2BLK;
  if (b < W3BLK) {                     // w3b [16,256]: rows 0..6 wl3, 8..14 wr3
    const int idx = b * 256 + threadIdx.x;
    if (idx < 16 * 256) {
      const int j = idx >> 8, k = idx & 255;
      float v = 0.0f;
      if (j < 7) v = wl3[(size_t)j * F2 + k];
      else if (j >= 8 && j < 15) v = wr3[(size_t)(j - 8) * F2 + k];
      w3b[idx] = f2b(v);
    }
    return;
  }
  b -= W3BLK;
  {                                    // degree count: 4 coalesced edges per thread
    const int base = b * 1024 + threadIdx.x;
#pragma unroll
    for (int k = 0; k < 4; ++k) {
      const int i = base + k * 256;
      if (i < E) atomicAdd(&cnt[dst[i]], 1);
    }
  }
}

// ---------------- gather-mean (bf16 in/out, f32 accum), C=512, wave per node ----------------
__global__ __launch_bounds__(256) void gather_mean_bf512(
    const unsigned short* __restrict__ xb, const int* __restrict__ row_ptr,
    const int* __restrict__ csr_src, unsigned short* __restrict__ aggb)
{
  const int node = blockIdx.x * 4 + (threadIdx.x >> 6);
  const int t = threadIdx.x & 63;
  if (node >= M_PAD) return;
  if (node >= N_NODES) {                // zero pad rows (deterministic)
    *reinterpret_cast<uint4*>(aggb + (size_t)node * 512 + t * 8) = make_uint4(0, 0, 0, 0);
    return;
  }
  const int beg = row_ptr[node];
  const int end = row_ptr[node + 1];
  float acc[8] = {0.f, 0.f, 0.f, 0.f, 0.f, 0.f, 0.f, 0.f};
  for (int j = beg; j < end; j += 8) {
    uint4 v[8];
    float m[8];
#pragma unroll
    for (int u = 0; u < 8; ++u) {
      const int e = min(j + u, end - 1);
      m[u] = (j + u < end) ? 1.0f : 0.0f;
      v[u] = *reinterpret_cast<const uint4*>(xb + (size_t)csr_src[e] * 512 + t * 8);
    }
#pragma unroll
    for (int u = 0; u < 8; ++u) {
      const unsigned int w[4] = {v[u].x, v[u].y, v[u].z, v[u].w};
#pragma unroll
      for (int q = 0; q < 4; ++q) {
        acc[2 * q]     = fmaf(m[u], b2f((unsigned short)(w[q] & 0xFFFF)), acc[2 * q]);
        acc[2 * q + 1] = fmaf(m[u], b2f((unsigned short)(w[q] >> 16)),    acc[2 * q + 1]);
      }
    }
  }
  const int deg = end - beg;
  const float inv = 1.0f / (float)(deg > 1 ? deg : 1);
  unsigned short r[8];
#pragma unroll
  for (int q = 0; q < 8; ++q) r[q] = f2b(acc[q] * inv);
  *reinterpret_cast<uint4*>(aggb + (size_t)node * 512 + t * 8) = *reinterpret_cast<const uint4*>(r);
}

// ---------------- 128x128 4-wave bf16 MFMA GEMM (single-buffer; settled best) ----------------
// niter=16: C = A1@B1.T + A2@B2.T (K=512 each);  niter=8: C = A1@B1.T.
__global__ __launch_bounds__(256) void gemm_mfma(
    const unsigned short* __restrict__ A1, const unsigned short* __restrict__ A2,
    const unsigned short* __restrict__ B1, const unsigned short* __restrict__ B2,
    const float* __restrict__ bias, unsigned short* __restrict__ Cout,
    int J, int niter, int fuse, int relu)
{
  __shared__ __align__(16) unsigned short Alds[128 * 64];
  __shared__ __align__(16) unsigned short Blds[128 * 64];
  const int tid = threadIdx.x;
  const int lane = tid & 63;
  const int wid = tid >> 6;          // 4 waves

  // XCD chunk swizzle over col-major flatten (nwg % 8 == 0: 2792/1396 for our shapes)
  const int nwg = gridDim.x * gridDim.y;
  int wg = blockIdx.y * gridDim.x + blockIdx.x;
  const int cpx = nwg >> 3;
  wg = (wg & 7) * cpx + (wg >> 3);
  const int brow = (wg / gridDim.y) * 128;   // consecutive wg on an XCD share the A row-panel
  const int bcol = (wg % gridDim.y) * 128;

  const int wr = wid >> 1;           // wave's 64x64 quadrant
  const int wc = wid & 1;

  f32x4 acc[4][4];
#pragma unroll
  for (int m = 0; m < 4; ++m)
#pragma unroll
    for (int n = 0; n < 4; ++n) acc[m][n] = (f32x4){0.f, 0.f, 0.f, 0.f};

  const int srow = lane >> 3;            // 0..7: row within 8-row stripe
  const int schunk = (lane & 7) ^ srow;  // T2: pre-swizzled source 16B-chunk (rule 21)
  const int fr = lane & 15;              // fragment row/col
  const int fk = lane >> 4;              // fragment k-group (8 elems)

  for (int it = 0; it < niter; ++it) {
    const unsigned short* __restrict__ A = (it < 8) ? A1 : A2;
    const unsigned short* __restrict__ B = (it < 8) ? B1 : B2;
    const int k0 = (it & 7) * 64;
    __syncthreads();                 // previous tile's reads done before overwrite
#pragma unroll
    for (int i = 0; i < 4; ++i) {
      const int rbase = i * 32 + wid * 8;   // wave-uniform 8-row stripe
      const int row = rbase + srow;
      __builtin_amdgcn_global_load_lds(
          (const __attribute__((address_space(1))) unsigned int*)(A + (size_t)(brow + row) * KP + k0 + schunk * 8),
          (__attribute__((address_space(3))) unsigned int*)(&Alds[rbase * 64]),
          16, 0, 0);
      __builtin_amdgcn_global_load_lds(
          (const __attribute__((address_space(1))) unsigned int*)(B + (size_t)(bcol + row) * KP + k0 + schunk * 8),
          (__attribute__((address_space(3))) unsigned int*)(&Blds[rbase * 64]),
          16, 0, 0);
    }
    __syncthreads();                 // staging visible (compiler drains vmcnt)
#pragma unroll
    for (int ks = 0; ks < 2; ++ks) {
      bf16x8 a[4], b[4];
#pragma unroll
      for (int m = 0; m < 4; ++m) {
        const int row = wr * 64 + m * 16 + fr;
        a[m] = *reinterpret_cast<const bf16x8*>(&Alds[row * 64 + (((ks * 4 + fk) ^ (row & 7)) * 8)]);
      }
#pragma unroll
      for (int n = 0; n < 4; ++n) {
        const int row = wc * 64 + n * 16 + fr;
        b[n] = *reinterpret_cast<const bf16x8*>(&Blds[row * 64 + (((ks * 4 + fk) ^ (row & 7)) * 8)]);
      }
#pragma unroll
      for (int m = 0; m < 4; ++m)
#pragma unroll
        for (int n = 0; n < 4; ++n)
          acc[m][n] = __builtin_amdgcn_mfma_f32_16x16x32_bf16(a[m], b[n], acc[m][n], 0, 0, 0);
    }
  }

  // epilogue: C/D layout col=lane&15, row=(lane>>4)*4+i  [m89-verified]
  const int crow0 = brow + wr * 64 + (lane >> 4) * 4;
  const int ccol0 = bcol + wc * 64 + (lane & 15);
#pragma unroll
  for (int n = 0; n < 4; ++n) {
    const int col = ccol0 + n * 16;
    const float bv = fuse ? bias[col] : 0.0f;
#pragma unroll
    for (int m = 0; m < 4; ++m) {
#pragma unroll
      for (int i = 0; i < 4; ++i) {
        const int row = crow0 + m * 16 + i;
        float v = acc[m][n][i] + bv;
        if (relu) v = fmaxf(v, 0.0f);
        Cout[(size_t)row * J + col] = f2b(v);
      }
    }
  }
}

// ---------------- fused layer-2 combine + layer-3 projection ----------------
__global__ __launch_bounds__(256) void combine2p3_kernel(
    const unsigned short* __restrict__ y, const int* __restrict__ row_ptr,
    const int* __restrict__ csr_src, const float* __restrict__ bias,
    const unsigned short* __restrict__ w3b, unsigned short* __restrict__ y3)
{
  __shared__ unsigned short w3s[16 * 256];
  {
    const int t0 = threadIdx.x * 16;
    *reinterpret_cast<uint4*>(&w3s[t0])     = *reinterpret_cast<const uint4*>(&w3b[t0]);
    *reinterpret_cast<uint4*>(&w3s[t0 + 8]) = *reinterpret_cast<const uint4*>(&w3b[t0 + 8]);
  }
  __syncthreads();

  const int node = blockIdx.x * 8 + (threadIdx.x >> 5);
  const int t = threadIdx.x & 31;        // 8 channels each -> 256
  if (node >= N_NODES) return;
  const int beg = row_ptr[node];
  const int end = row_ptr[node + 1];
  float acc[8] = {0.f, 0.f, 0.f, 0.f, 0.f, 0.f, 0.f, 0.f};
  for (int j = beg; j < end; j += 8) {
    uint4 v[8];
    float m[8];
#pragma unroll
    for (int u = 0; u < 8; ++u) {
      const int e = min(j + u, end - 1);
      m[u] = (j + u < end) ? 1.0f : 0.0f;
      v[u] = *reinterpret_cast<const uint4*>(y + (size_t)csr_src[e] * 512 + t * 8);
    }
#pragma unroll
    for (int u = 0; u < 8; ++u) {
      const unsigned int w[4] = {v[u].x, v[u].y, v[u].z, v[u].w};
#pragma unroll
      for (int q = 0; q < 4; ++q) {
        acc[2 * q]     = fmaf(m[u], b2f((unsigned short)(w[q] & 0xFFFF)), acc[2 * q]);
        acc[2 * q + 1] = fmaf(m[u], b2f((unsigned short)(w[q] >> 16)),    acc[2 * q + 1]);
      }
    }
  }
  const int deg = end - beg;
  const float inv = 1.0f / (float)(deg > 1 ? deg : 1);
  const uint4 rv = *reinterpret_cast<const uint4*>(y + (size_t)node * 512 + 256 + t * 8);
  const unsigned int ru[4] = {rv.x, rv.y, rv.z, rv.w};
  float c[8];
#pragma unroll
  for (int q = 0; q < 4; ++q) {
    const float y0 = b2f((unsigned short)(ru[q] & 0xFFFF));
    const float y1 = b2f((unsigned short)(ru[q] >> 16));
    c[2 * q]     = fmaxf(acc[2 * q] * inv + y0 + bias[t * 8 + 2 * q], 0.0f);
    c[2 * q + 1] = fmaxf(acc[2 * q + 1] * inv + y1 + bias[t * 8 + 2 * q + 1], 0.0f);
  }
#pragma unroll
  for (int jj = 0; jj < 14; ++jj) {
    const int row = jj + (jj >= 7 ? 1 : 0);      // skip padding rows 7/15
    const uint4 wv = *reinterpret_cast<const uint4*>(&w3s[row * 256 + t * 8]);
    const unsigned int wu[4] = {wv.x, wv.y, wv.z, wv.w};
    float s = 0.0f;
#pragma unroll
    for (int q = 0; q < 4; ++q) {
      s = fmaf(c[2 * q],     b2f((unsigned short)(wu[q] & 0xFFFF)), s);
      s = fmaf(c[2 * q + 1], b2f((unsigned short)(wu[q] >> 16)),    s);
    }
#pragma unroll
    for (int m = 1; m < 32; m <<= 1) s += __shfl_xor(s, m, 64);
    if (t == 0) y3[(size_t)node * 16 + row] = f2b(s);
  }
}

// ---------------- combine layer 3: out = mean-gather(y3[:, 0..6]) + y3[i, 8..14] + b3 ----------------
__global__ __launch_bounds__(256) void combine3_kernel(
    const unsigned short* __restrict__ y3, const int* __restrict__ row_ptr,
    const int* __restrict__ csr_src, const float* __restrict__ b3,
    float* __restrict__ out, int N)
{
  const int node = blockIdx.x * 4 + (threadIdx.x >> 6);
  const int lane = threadIdx.x & 63;
  if (node >= N) return;
  const int beg = row_ptr[node];
  const int end = row_ptr[node + 1];
  float acc[7] = {0.f, 0.f, 0.f, 0.f, 0.f, 0.f, 0.f};
  for (int j = beg + lane; j < end; j += 64) {
    const int s = csr_src[j];
    const uint4 v = *reinterpret_cast<const uint4*>(y3 + (size_t)s * 16);
    const unsigned int u[4] = {v.x, v.y, v.z, v.w};
#pragma unroll
    for (int q = 0; q < 7; ++q) {
      const unsigned short hw = (unsigned short)((u[q >> 1] >> ((q & 1) * 16)) & 0xFFFF);
      acc[q] += b2f(hw);
    }
  }
#pragma unroll
  for (int q = 0; q < 7; ++q)
#pragma unroll
    for (int m = 1; m < 64; m <<= 1)
      acc[q] += __shfl_xor(acc[q], m, 64);
  if (lane == 0) {
    const int deg = end - beg;
    const float inv = 1.0f / (float)(deg > 1 ? deg : 1);
    const uint4 rv = *reinterpret_cast<const uint4*>(y3 + (size_t)node * 16 + 8);
    const unsigned int ru[4] = {rv.x, rv.y, rv.z, rv.w};
#pragma unroll
    for (int q = 0; q < 7; ++q) {
      const float self = b2f((unsigned short)((ru[q >> 1] >> ((q & 1) * 16)) & 0xFFFF));
      out[(size_t)node * F3 + q] = acc[q] * inv + self + b3[q];
    }
  }
}

extern "C" void kernel_launch(void* const* d_in, const int* in_sizes, int n_in,
                              void* d_out, int out_size, void* d_ws, size_t ws_size,
                              hipStream_t stream) {
  const float* x    = (const float*)d_in[0];
  const int*   ei   = (const int*)d_in[1];
  const float* w_l1 = (const float*)d_in[2];
  const float* w_r1 = (const float*)d_in[3];
  const float* b1   = (const float*)d_in[4];
  const float* w_l2 = (const float*)d_in[5];
  const float* w_r2 = (const float*)d_in[6];
  const float* b2   = (const float*)d_in[7];
  const float* w_l3 = (const float*)d_in[8];
  const float* w_r3 = (const float*)d_in[9];
  const float* b3   = (const float*)d_in[10];
  float* out = (float*)d_out;

  const int E = in_sizes[1] / 2;
  const int* src = ei;
  const int* dst = ei + E;

  // ---- workspace carve-up
  char* p = (char*)d_ws;
  int* row_ptr = (int*)p;           p += (size_t)(N_NODES + 1) * 4;
  int* cnt     = (int*)p;           p += (size_t)N_NODES * 4;
  int* bsum    = (int*)p;           p += 1024 * 4;
  int* csr_src = (int*)p;           p += (size_t)E * 4;
  p = (char*)(((uintptr_t)p + 255) & ~(uintptr_t)255);
  unsigned short* xb   = (unsigned short*)p;  p += (size_t)M_PAD * KP * 2;  // also reused as y2
  unsigned short* aggb = (unsigned short*)p;  p += (size_t)M_PAD * KP * 2;
  unsigned short* h1b  = (unsigned short*)p;  p += (size_t)M_PAD * KP * 2;  // also reused as y3
  unsigned short* wl1b = (unsigned short*)p;  p += (size_t)F1 * KP * 2;
  unsigned short* wr1b = (unsigned short*)p;  p += (size_t)F1 * KP * 2;
  unsigned short* w2b  = (unsigned short*)p;  p += (size_t)F1 * KP * 2;     // concat [wl2; wr2] -> 512 rows
  unsigned short* w3b  = (unsigned short*)p;  p += (size_t)16 * F2 * 2;     // [16,256]

  unsigned short* y2  = xb;     // [M_PAD, 512]; xb dead after GEMM1
  unsigned short* y3  = h1b;    // [M_PAD, 16];  h1b dead after GEMM2

  const int nb = cdiv_i(N_NODES, 1024);   // 88
  const int dblk = cdiv_i(E, 1024);       // 879

  // ---- prep (x + weights + degree count, one kernel)
  hipMemsetAsync(cnt, 0, (size_t)N_NODES * sizeof(int), stream);
  prep_kernel<<<XBLK + W1BLK + W2BLK + W3BLK + dblk, 256, 0, stream>>>(
      x, w_l1, w_r1, w_l2, w_r2, w_l3, w_r3, xb, wl1b, wr1b, w2b, w3b,
      dst, cnt, E);

  // ---- CSR build (scan + fill)
  scan_partial<<<nb, 1024, 0, stream>>>(cnt, row_ptr, bsum, N_NODES);
  scan_add_fused<<<nb, 1024, 0, stream>>>(row_ptr, bsum, cnt, N_NODES, E, nb);   // cnt becomes cursor
  fill_kernel<<<cdiv_i(E, 256), 256, 0, stream>>>(src, dst, cnt, csr_src, E);

  // ---- layer 1: agg = mean-gather(x);  h1 = relu(agg@wl1.T + x@wr1.T + b1)
  gather_mean_bf512<<<cdiv_i(M_PAD, 4), 256, 0, stream>>>(xb, row_ptr, csr_src, aggb);
  {
    dim3 g(M_PAD / 128, F1 / 128);
    gemm_mfma<<<g, 256, 0, stream>>>(aggb, xb, wl1b, wr1b, b1, h1b, F1, 16, 1, 1);
  }

  // ---- layer 2 (aggregate AFTER projection): y2 = h1 @ [wl2; wr2].T
  {
    dim3 g(M_PAD / 128, 512 / 128);
    gemm_mfma<<<g, 256, 0, stream>>>(h1b, h1b, w2b, w2b, (const float*)nullptr, y2, 512, 8, 0, 0);
  }
  // fused: combine layer 2 + project layer 3 (h2 never materialized)
  combine2p3_kernel<<<cdiv_i(N_NODES, 8), 256, 0, stream>>>(y2, row_ptr, csr_src, b2, w3b, y3);

  // ---- combine layer 3
  combine3_kernel<<<cdiv_i(N_NODES, 4), 256, 0, stream>>>(y3, row_ptr, csr_src, b3, out, N_NODES);
}